// Round 15
// baseline (872.201 us; speedup 1.0000x reference)
//
#include <hip/hip_runtime.h>
#include <hip/hip_bf16.h>

#define EPSF 1e-8f

typedef __attribute__((ext_vector_type(8))) short short8v;
typedef __attribute__((ext_vector_type(4))) float float4v;

static __device__ __forceinline__ unsigned short f2bf_bits(float x)
{
    return __builtin_bit_cast(unsigned short, __float2bfloat16(x));
}

// ---------------------------------------------------------------------------
// Bw2 transform: pc_w f32 [256oc][256ic][81k] -> coalesced per-wave chunks:
//   chunk_id = ((kidx*8+icc)*4+wc)*4+nt ; within chunk lane(slot*16+r16)*8+i
// ---------------------------------------------------------------------------
__global__ __launch_bounds__(256) void k_bw2(const float* __restrict__ pw,
                                             __hip_bfloat16* __restrict__ Bw2)
{
    const int oc = blockIdx.x;
    const int t = threadIdx.x;
    __shared__ unsigned short wl[20736];   // [ic][k] bf16 bits
    for (int i = t; i < 20736; i += 256)
        wl[i] = f2bf_bits(pw[(size_t)oc * 20736 + i]);
    __syncthreads();
    const int r16 = oc & 15, nt = (oc >> 4) & 3, wcq = oc >> 6;
    for (int e = t; e < 2592; e += 256) {
        const int kidx = e >> 5, icc = (e >> 2) & 7, slot = e & 3;
        short8v v;
        #pragma unroll
        for (int i = 0; i < 8; ++i)
            v[i] = (short)wl[(icc * 32 + slot * 8 + i) * 81 + kidx];
        const int chunk = ((kidx * 8 + icc) * 4 + wcq) * 4 + nt;
        *(short8v*)(Bw2 + (size_t)chunk * 512 + (slot * 16 + r16) * 8) = v;
    }
}

// ---------------------------------------------------------------------------
// conv1: image[512,1,28,28] * cw[256,1,9,9] + cb -> relu
//   -> x_t bf16 [b][icc=8][pos=400][64B unit, slot-XOR-permuted]
//   pos = h*20 + (w&1)*10 + (w>>1); unit byte: ((slot ^ ((pos>>1)&3))<<4)+ic8*2
// ---------------------------------------------------------------------------
__global__ __launch_bounds__(256) void k_conv1(const float* __restrict__ img,
                                               const float* __restrict__ cw,
                                               const float* __restrict__ cb,
                                               __hip_bfloat16* __restrict__ xt)
{
    const int b = blockIdx.x;
    const int c = threadIdx.x;
    __shared__ float simg[784];
    for (int i = c; i < 784; i += 256) simg[i] = img[b * 784 + i];
    float wreg[81];
    const float* wp = cw + c * 81;
    #pragma unroll
    for (int k = 0; k < 81; ++k) wreg[k] = wp[k];
    const float bias = cb[c];
    __syncthreads();

    const int icc = c >> 5, slot = (c >> 3) & 3, ic8 = c & 7;
    char* xbase = (char*)xt + ((size_t)b * 8 + icc) * 25600;

    for (int h = 0; h < 20; ++h) {
        for (int wg = 0; wg < 5; ++wg) {
            float acc[4] = {bias, bias, bias, bias};
            #pragma unroll
            for (int ky = 0; ky < 9; ++ky) {
                const float* rp = &simg[(h + ky) * 28 + wg * 4];
                float v[12];
                #pragma unroll
                for (int i = 0; i < 12; ++i) v[i] = rp[i];
                #pragma unroll
                for (int kx = 0; kx < 9; ++kx) {
                    const float wv = wreg[ky * 9 + kx];
                    #pragma unroll
                    for (int i = 0; i < 4; ++i)
                        acc[i] = fmaf(v[kx + i], wv, acc[i]);
                }
            }
            #pragma unroll
            for (int i = 0; i < 4; ++i) {
                int w = wg * 4 + i;
                float av = fmaxf(acc[i], 0.f);
                int pos = h * 20 + (w & 1) * 10 + (w >> 1);
                int off = pos * 64 + ((slot ^ ((pos >> 1) & 3)) << 4) + ic8 * 2;
                *(unsigned short*)(xbase + off) = f2bf_bits(av);
            }
        }
    }
}

// ---------------------------------------------------------------------------
// async stage of one icc-chunk (2 images, 51200 B) into LDS; 256 threads.
// ---------------------------------------------------------------------------
__device__ __forceinline__ void stage_x(const __hip_bfloat16* __restrict__ xt,
                                        char* dst, int b0, int icc, int t)
{
    const __hip_bfloat16* base0 = xt + ((size_t)(b0    ) * 8 + icc) * 12800;
    const __hip_bfloat16* base1 = xt + ((size_t)(b0 + 1) * 8 + icc) * 12800;
    #pragma unroll
    for (int k = 0; k < 12; ++k) {
        const int unit = t + k * 256;
        const __hip_bfloat16* gp = (unit < 1600) ? (base0 + unit * 8)
                                                 : (base1 + (unit - 1600) * 8);
        __builtin_amdgcn_global_load_lds(
            (const __attribute__((address_space(1))) unsigned int*)gp,
            (__attribute__((address_space(3))) unsigned int*)(dst + unit * 16),
            16, 0, 0);
    }
    if (t < 128) {
        const int unit = 3072 + t;
        const __hip_bfloat16* gp = base1 + (unit - 1600) * 8;
        __builtin_amdgcn_global_load_lds(
            (const __attribute__((address_space(1))) unsigned int*)gp,
            (__attribute__((address_space(3))) unsigned int*)(dst + unit * 16),
            16, 0, 0);
    }
}

// ---------------------------------------------------------------------------
// conv2 via MFMA, packed-M: grid 256 (2 img each), 256 thr = 4 waves (wc).
// Rows of BOTH images packed into 5 shared 16-row tiles (72/80 valid) ->
// 20 MFMA per 4KB B-load (1.67x R8), half the waves -> half the B L2 issue.
// Single-buffered 51.2KB LDS -> 3 blocks/CU (12 waves/CU), 2 barriers/icc.
// ---------------------------------------------------------------------------
__global__ __launch_bounds__(256, 3) void k_conv2(const __hip_bfloat16* __restrict__ xt,
                                                  const __hip_bfloat16* __restrict__ Bw2,
                                                  const float* __restrict__ pcb,
                                                  float* __restrict__ u)
{
    const int b0 = blockIdx.x * 2;
    const int t = threadIdx.x;
    const int lane = t & 63, wc = t >> 6;
    const int r16 = lane & 15, slot = lane >> 4;

    __shared__ alignas(16) char xs[51200];

    // 5 row-tiles cover grow = 0..79; grow = img*36 + hw for grow < 72
    int aimg[5], lc[5];
    #pragma unroll
    for (int mt = 0; mt < 5; ++mt) {
        int grow = mt * 16 + r16;
        int img = (grow >= 36 && grow < 72) ? 1 : 0;
        int hw = (grow < 72) ? (grow - 36 * img) : 0;
        int h = hw / 6, w = hw - h * 6;
        aimg[mt] = img * 25600;
        lc[mt] = 40 * h + w;
    }

    float4v acc[5][4];
    #pragma unroll
    for (int mt = 0; mt < 5; ++mt)
        #pragma unroll
        for (int nt = 0; nt < 4; ++nt)
            acc[mt][nt] = (float4v){0.f, 0.f, 0.f, 0.f};

    for (int icc = 0; icc < 8; ++icc) {
        __syncthreads();                       // waves done reading xs
        stage_x(xt, xs, b0, icc, t);
        __syncthreads();                       // stage complete (vmcnt drained)

        const __hip_bfloat16* bp = Bw2 + ((size_t)icc * 4 + wc) * 2048 + lane * 8;

        #pragma unroll 3
        for (int kidx = 0; kidx < 81; ++kidx) {
            int ky = kidx / 9, kx = kidx - ky * 9;
            int scalK = 20 * ky + 10 * (kx & 1) + (kx >> 1);
            short8v a[5];
            #pragma unroll
            for (int mt = 0; mt < 5; ++mt) {
                int pos = lc[mt] + scalK;
                int off = aimg[mt] + pos * 64 + (((slot ^ (pos >> 1)) & 3) << 4);
                a[mt] = *(const short8v*)(xs + off);
            }
            const __hip_bfloat16* bq = bp + (size_t)kidx * 65536;
            short8v bv[4];
            #pragma unroll
            for (int nt = 0; nt < 4; ++nt)
                bv[nt] = *(const short8v*)(bq + nt * 512);
            #pragma unroll
            for (int mt = 0; mt < 5; ++mt)
                #pragma unroll
                for (int nt = 0; nt < 4; ++nt)
                    acc[mt][nt] = __builtin_amdgcn_mfma_f32_16x16x32_bf16(a[mt], bv[nt], acc[mt][nt], 0, 0, 0);
        }
    }

    // epilogue: D row grow = mt*16 + slot*4 + i (36%4==0 -> blocks never
    // straddle an image boundary); col(oc) = r16.
    #pragma unroll
    for (int mt = 0; mt < 5; ++mt) {
        int grow0 = mt * 16 + slot * 4;
        if (grow0 < 72) {
            int img = grow0 >= 36;
            int hwb = grow0 - 36 * img;
            const int b = b0 + img;
            #pragma unroll
            for (int nt = 0; nt < 4; ++nt) {
                int oc = wc * 64 + nt * 16 + r16;
                float pb = pcb[oc];
                float4v v = acc[mt][nt];
                v.x += pb; v.y += pb; v.z += pb; v.w += pb;
                *(float4v*)(u + (size_t)b * 9216 + oc * 36 + hwb) = v;
            }
        }
    }
}

// ---------------------------------------------------------------------------
// squash groups of 8 (in place)
// ---------------------------------------------------------------------------
__global__ void k_squash_u(float* __restrict__ u, int ngroups)
{
    int g = blockIdx.x * blockDim.x + threadIdx.x;
    if (g >= ngroups) return;
    float4v* p = (float4v*)(u + (size_t)g * 8);
    float4v a = p[0], c = p[1];
    float sq = a.x * a.x + a.y * a.y + a.z * a.z + a.w * a.w
             + c.x * c.x + c.y * c.y + c.z * c.z + c.w * c.w;
    float scale = (sq / (1.f + sq)) / sqrtf(sq + EPSF);
    a *= scale; c *= scale;
    p[0] = a; p[1] = c;
}

// ---------------------------------------------------------------------------
// routing: grid 576 = 144 rc (8 W-rows) x 4 bc (128 images); 256 thr.
// Thread = (oq, img) handles TWO images; W LDS-reads shared by both.
// ---------------------------------------------------------------------------
__global__ __launch_bounds__(256, 2) void k_route3(const float* __restrict__ u,
                                                   const float* __restrict__ W,
                                                   const float* __restrict__ vsum,
                                                   float* __restrict__ spart, int iter)
{
    const int bid = blockIdx.x;
    const int rc = bid % 144;
    const int bc = bid / 144;          // 0..3
    const int r0 = rc * 8;
    const int b0 = bc * 128;
    const int t = threadIdx.x;
    const int oq = t & 3;
    const int img = t >> 2;            // 0..63
    const int bA = b0 + img, bB = bA + 64;

    __shared__ alignas(16) float Wl[10240];     // 40KB: 8 rows x 320 f4, swizzled
    __shared__ alignas(16) float ul[128 * 68];  // 34.8KB: u tile, stride 68

    #pragma unroll
    for (int k = 0; k < 10; ++k) {
        int e = t + k * 256;
        int rr = e / 320, rest = e - rr * 320;
        float4v val = *(const float4v*)(W + (size_t)(r0 + rr) * 1280 + rest * 4);
        int es = e ^ ((e >> 3) & 3);
        *(float4v*)(Wl + es * 4) = val;
    }
    #pragma unroll
    for (int k = 0; k < 8; ++k) {
        int e = t + k * 256;           // 0..2047
        int im = e >> 4, f4 = e & 15;
        float4v val = *(const float4v*)(u + (size_t)(b0 + im) * 9216 + rc * 64 + f4 * 4);
        *(float4v*)(ul + im * 68 + f4 * 4) = val;
    }
    __syncthreads();

    float4v accA[10], accB[10];
    #pragma unroll
    for (int j = 0; j < 10; ++j) {
        accA[j] = (float4v){0.f, 0.f, 0.f, 0.f};
        accB[j] = (float4v){0.f, 0.f, 0.f, 0.f};
    }

    const float* upA = ul + img * 68;
    const float* upB = ul + (img + 64) * 68;

    for (int r = 0; r < 8; ++r) {
        float4v uA0 = *(const float4v*)(upA + r * 8);
        float4v uA1 = *(const float4v*)(upA + r * 8 + 4);
        float4v uB0 = *(const float4v*)(upB + r * 8);
        float4v uB1 = *(const float4v*)(upB + r * 8 + 4);
        float4v uhA[10], uhB[10];
        #pragma unroll
        for (int j = 0; j < 10; ++j) {
            #pragma unroll
            for (int oo = 0; oo < 4; ++oo) {
                int un = r * 320 + j * 32 + oq * 8 + oo * 2;
                int i0 = un ^ oq;      // (un>>3)&3 == oq here
                int i1 = i0 ^ 1;
                float4v wlo = *(const float4v*)(Wl + i0 * 4);
                float4v whi = *(const float4v*)(Wl + i1 * 4);
                uhA[j][oo] = wlo.x * uA0.x + wlo.y * uA0.y + wlo.z * uA0.z + wlo.w * uA0.w
                           + whi.x * uA1.x + whi.y * uA1.y + whi.z * uA1.z + whi.w * uA1.w;
                uhB[j][oo] = wlo.x * uB0.x + wlo.y * uB0.y + wlo.z * uB0.z + wlo.w * uB0.w
                           + whi.x * uB1.x + whi.y * uB1.y + whi.z * uB1.z + whi.w * uB1.w;
            }
        }
        if (iter > 0) {
            #pragma unroll 2
            for (int half = 0; half < 2; ++half) {
                const int b = half ? bB : bA;
                float4v* uh = half ? uhB : uhA;
                float4v* acc = half ? accB : accA;
                float q[10];
                #pragma unroll
                for (int j = 0; j < 10; ++j) {
                    float4v vj = *(const float4v*)(vsum + (size_t)b * 160 + j * 16 + oq * 4);
                    float qp = uh[j].x * vj.x + uh[j].y * vj.y
                             + uh[j].z * vj.z + uh[j].w * vj.w;
                    qp += __shfl_xor(qp, 1);
                    qp += __shfl_xor(qp, 2);
                    q[j] = qp;
                }
                float mx = q[0];
                #pragma unroll
                for (int j = 1; j < 10; ++j) mx = fmaxf(mx, q[j]);
                float ssum = 0.f;
                float c[10];
                #pragma unroll
                for (int j = 0; j < 10; ++j) { c[j] = __expf(q[j] - mx); ssum += c[j]; }
                float inv = 1.f / ssum;
                #pragma unroll
                for (int j = 0; j < 10; ++j) acc[j] += (c[j] * inv) * uh[j];
            }
        } else {
            #pragma unroll
            for (int j = 0; j < 10; ++j) {
                accA[j] += 0.1f * uhA[j];
                accB[j] += 0.1f * uhB[j];
            }
        }
    }

    float* dstA = spart + ((size_t)rc * 512 + bA) * 160 + oq * 4;
    float* dstB = spart + ((size_t)rc * 512 + bB) * 160 + oq * 4;
    #pragma unroll
    for (int j = 0; j < 10; ++j) {
        *(float4v*)(dstA + j * 16) = accA[j];
        *(float4v*)(dstB + j * 16) = accB[j];
    }
}

// ---------------------------------------------------------------------------
// finish: sum 144 partials -> squash -> v; vsum update; iter==2 writes outputs
// ---------------------------------------------------------------------------
__global__ void k_finish(const float* __restrict__ spart, float* __restrict__ vsum,
                         const int* __restrict__ label, float* __restrict__ obj,
                         float* __restrict__ yprob, float* __restrict__ masked, int iter)
{
    const int b = blockIdx.x, t = threadIdx.x;
    if (t < 160) {
        const float* sp = spart + (size_t)b * 160 + t;
        float sv = 0.f;
        #pragma unroll 8
        for (int rc = 0; rc < 144; ++rc)
            sv += sp[(size_t)rc * 81920];
        float sq = sv * sv;
        sq += __shfl_xor(sq, 1); sq += __shfl_xor(sq, 2);
        sq += __shfl_xor(sq, 4); sq += __shfl_xor(sq, 8);
        float v = sv * (sq / (1.f + sq)) / sqrtf(sq + EPSF);
        float pv = (iter > 0) ? vsum[b * 160 + t] : 0.f;
        vsum[b * 160 + t] = pv + v;
        if (iter == 2) {
            obj[b * 160 + t] = v;
            float vv = v * v;
            vv += __shfl_xor(vv, 1); vv += __shfl_xor(vv, 2);
            vv += __shfl_xor(vv, 4); vv += __shfl_xor(vv, 8);
            int j = t >> 4;
            if ((t & 15) == 0) yprob[b * 10 + j] = sqrtf(vv + EPSF);
            masked[b * 160 + t] = (label[b] == j) ? v : 0.f;
        }
    }
}

// ---------------------------------------------------------------------------
// decoder GEMM: C[m,n] = act(bias[n] + sum_k A[m,k]*Wt[n,k]); M=512.
// ---------------------------------------------------------------------------
__global__ void k_mlp(const float* __restrict__ A, const float* __restrict__ Wt,
                      const float* __restrict__ bias, float* __restrict__ C,
                      int N, int K, int act)
{
    const int m0 = blockIdx.x * 32;
    const int n0 = blockIdx.y * 32;
    const int t  = threadIdx.x;
    const int tn = t & 31, tg = t >> 5;
    __shared__ float As[32][33];
    __shared__ float Ws[32][33];
    float acc[4] = {0.f, 0.f, 0.f, 0.f};
    for (int k0 = 0; k0 < K; k0 += 32) {
        __syncthreads();
        for (int idx = t; idx < 1024; idx += 256) {
            int rr = idx >> 5, kk = idx & 31;
            As[rr][kk] = A[(size_t)(m0 + rr) * K + k0 + kk];
            int n = n0 + rr;
            Ws[rr][kk] = (n < N) ? Wt[(size_t)n * K + k0 + kk] : 0.f;
        }
        __syncthreads();
        #pragma unroll 8
        for (int kk = 0; kk < 32; ++kk) {
            float bv = Ws[tn][kk];
            #pragma unroll
            for (int i = 0; i < 4; ++i)
                acc[i] += As[tg * 4 + i][kk] * bv;
        }
    }
    int n = n0 + tn;
    if (n < N) {
        float bs = bias[n];
        #pragma unroll
        for (int i = 0; i < 4; ++i) {
            float vv = acc[i] + bs;
            vv = (act == 0) ? fmaxf(vv, 0.f) : 1.f / (1.f + expf(-vv));
            C[(size_t)(m0 + tg * 4 + i) * N + n] = vv;
        }
    }
}

// ---------------------------------------------------------------------------
extern "C" void kernel_launch(void* const* d_in, const int* in_sizes, int n_in,
                              void* d_out, int out_size, void* d_ws, size_t ws_size,
                              hipStream_t stream)
{
    const float* image  = (const float*)d_in[0];
    const int*   label  = (const int*)  d_in[1];
    const float* conv_w = (const float*)d_in[2];
    const float* conv_b = (const float*)d_in[3];
    const float* pc_w   = (const float*)d_in[4];
    const float* pc_b   = (const float*)d_in[5];
    const float* Wrt    = (const float*)d_in[6];
    const float* dw1 = (const float*)d_in[7];
    const float* db1 = (const float*)d_in[8];
    const float* dw2 = (const float*)d_in[9];
    const float* db2 = (const float*)d_in[10];
    const float* dw3 = (const float*)d_in[11];
    const float* db3 = (const float*)d_in[12];
    float* out = (float*)d_out;

    char* p = (char*)d_ws;
    __hip_bfloat16* xt  = (__hip_bfloat16*)p; p += 104857600;
    float* u      = (float*)p; p += 18874368;
    __hip_bfloat16* Bw2 = (__hip_bfloat16*)p; p += 10616832;
    float* vsum   = (float*)p; p += 327680;
    float* masked = (float*)p; p += 327680;
    float* h1     = (float*)p; p += 1048576;
    float* h2     = (float*)p; p += 2097152;

    // spart [144][512][160] f32 (47.2 MB) aliases xt (dead after k_conv2,
    // fully rewritten by conv1 each launch -> deterministic across replays).
    float* spart = (float*)xt;

    float* obj   = out;            // [512,10,16,1]
    float* recon = out + 81920;    // [512,1,28,28]
    float* yprob = out + 483328;   // [512,10]

    k_bw2<<<256, 256, 0, stream>>>(pc_w, Bw2);
    k_conv1<<<512, 256, 0, stream>>>(image, conv_w, conv_b, xt);
    k_conv2<<<256, 256, 0, stream>>>(xt, Bw2, pc_b, u);
    k_squash_u<<<2304, 256, 0, stream>>>(u, 589824);
    for (int it = 0; it < 3; ++it) {
        k_route3<<<576, 256, 0, stream>>>(u, Wrt, vsum, spart, it);
        k_finish<<<512, 192, 0, stream>>>(spart, vsum, label, obj, yprob, masked, it);
    }
    k_mlp<<<dim3(16, 16), 256, 0, stream>>>(masked, dw1, db1, h1, 512, 160, 0);
    k_mlp<<<dim3(16, 32), 256, 0, stream>>>(h1, dw2, db2, h2, 1024, 512, 0);
    k_mlp<<<dim3(16, 25), 256, 0, stream>>>(h2, dw3, db3, recon, 784, 1024, 1);
}

// Round 16
// 710.943 us; speedup vs baseline: 1.2268x; 1.2268x over previous
//
#include <hip/hip_runtime.h>
#include <hip/hip_bf16.h>

#define EPSF 1e-8f

typedef __attribute__((ext_vector_type(8))) short short8v;
typedef __attribute__((ext_vector_type(4))) float float4v;

static __device__ __forceinline__ unsigned short f2bf_bits(float x)
{
    return __builtin_bit_cast(unsigned short, __float2bfloat16(x));
}

// ---------------------------------------------------------------------------
// Bw2 transform: pc_w f32 [256oc][256ic][81k] -> coalesced per-wave chunks:
//   chunk_id = ((kidx*8+icc)*4+wc)*4+nt ; within chunk lane(slot*16+r16)*8+i
// ---------------------------------------------------------------------------
__global__ __launch_bounds__(256) void k_bw2(const float* __restrict__ pw,
                                             __hip_bfloat16* __restrict__ Bw2)
{
    const int oc = blockIdx.x;
    const int t = threadIdx.x;
    __shared__ unsigned short wl[20736];   // [ic][k] bf16 bits
    for (int i = t; i < 20736; i += 256)
        wl[i] = f2bf_bits(pw[(size_t)oc * 20736 + i]);
    __syncthreads();
    const int r16 = oc & 15, nt = (oc >> 4) & 3, wcq = oc >> 6;
    for (int e = t; e < 2592; e += 256) {
        const int kidx = e >> 5, icc = (e >> 2) & 7, slot = e & 3;
        short8v v;
        #pragma unroll
        for (int i = 0; i < 8; ++i)
            v[i] = (short)wl[(icc * 32 + slot * 8 + i) * 81 + kidx];
        const int chunk = ((kidx * 8 + icc) * 4 + wcq) * 4 + nt;
        *(short8v*)(Bw2 + (size_t)chunk * 512 + (slot * 16 + r16) * 8) = v;
    }
}

// ---------------------------------------------------------------------------
// conv1: image[512,1,28,28] * cw[256,1,9,9] + cb -> relu
//   -> x_t bf16 [b][icc=8][pos=400][64B unit, slot-XOR-permuted]
//   pos = h*20 + (w&1)*10 + (w>>1); unit byte: ((slot ^ ((pos>>1)&3))<<4)+ic8*2
// ---------------------------------------------------------------------------
__global__ __launch_bounds__(256) void k_conv1(const float* __restrict__ img,
                                               const float* __restrict__ cw,
                                               const float* __restrict__ cb,
                                               __hip_bfloat16* __restrict__ xt)
{
    const int b = blockIdx.x;
    const int c = threadIdx.x;
    __shared__ float simg[784];
    for (int i = c; i < 784; i += 256) simg[i] = img[b * 784 + i];
    float wreg[81];
    const float* wp = cw + c * 81;
    #pragma unroll
    for (int k = 0; k < 81; ++k) wreg[k] = wp[k];
    const float bias = cb[c];
    __syncthreads();

    const int icc = c >> 5, slot = (c >> 3) & 3, ic8 = c & 7;
    char* xbase = (char*)xt + ((size_t)b * 8 + icc) * 25600;

    for (int h = 0; h < 20; ++h) {
        for (int wg = 0; wg < 5; ++wg) {
            float acc[4] = {bias, bias, bias, bias};
            #pragma unroll
            for (int ky = 0; ky < 9; ++ky) {
                const float* rp = &simg[(h + ky) * 28 + wg * 4];
                float v[12];
                #pragma unroll
                for (int i = 0; i < 12; ++i) v[i] = rp[i];
                #pragma unroll
                for (int kx = 0; kx < 9; ++kx) {
                    const float wv = wreg[ky * 9 + kx];
                    #pragma unroll
                    for (int i = 0; i < 4; ++i)
                        acc[i] = fmaf(v[kx + i], wv, acc[i]);
                }
            }
            #pragma unroll
            for (int i = 0; i < 4; ++i) {
                int w = wg * 4 + i;
                float av = fmaxf(acc[i], 0.f);
                int pos = h * 20 + (w & 1) * 10 + (w >> 1);
                int off = pos * 64 + ((slot ^ ((pos >> 1) & 3)) << 4) + ic8 * 2;
                *(unsigned short*)(xbase + off) = f2bf_bits(av);
            }
        }
    }
}

// ---------------------------------------------------------------------------
// async stage of one icc-chunk (2 images, 51200 B) into LDS; 256 threads.
// ---------------------------------------------------------------------------
__device__ __forceinline__ void stage_x(const __hip_bfloat16* __restrict__ xt,
                                        char* dst, int b0, int icc, int t)
{
    const __hip_bfloat16* base0 = xt + ((size_t)(b0    ) * 8 + icc) * 12800;
    const __hip_bfloat16* base1 = xt + ((size_t)(b0 + 1) * 8 + icc) * 12800;
    #pragma unroll
    for (int k = 0; k < 12; ++k) {
        const int unit = t + k * 256;
        const __hip_bfloat16* gp = (unit < 1600) ? (base0 + unit * 8)
                                                 : (base1 + (unit - 1600) * 8);
        __builtin_amdgcn_global_load_lds(
            (const __attribute__((address_space(1))) unsigned int*)gp,
            (__attribute__((address_space(3))) unsigned int*)(dst + unit * 16),
            16, 0, 0);
    }
    if (t < 128) {
        const int unit = 3072 + t;
        const __hip_bfloat16* gp = base1 + (unit - 1600) * 8;
        __builtin_amdgcn_global_load_lds(
            (const __attribute__((address_space(1))) unsigned int*)gp,
            (__attribute__((address_space(3))) unsigned int*)(dst + unit * 16),
            16, 0, 0);
    }
}

// ---------------------------------------------------------------------------
// conv2 via MFMA, packed-M + K-split: grid 512 = 256 pairs x 2 ks (4 icc each).
// 256 thr = 4 waves (wc). Rows of BOTH images packed into 5 shared 16-row
// tiles -> 20 MFMA per 4KB B-load; K-split gives 2 blocks/CU (8 waves/CU)
// while each wave issues only 1.3MB of B. Partials -> u0 (ks0,+bias) / u1.
// ---------------------------------------------------------------------------
__global__ __launch_bounds__(256, 2) void k_conv2(const __hip_bfloat16* __restrict__ xt,
                                                  const __hip_bfloat16* __restrict__ Bw2,
                                                  const float* __restrict__ pcb,
                                                  float* __restrict__ u0,
                                                  float* __restrict__ u1)
{
    const int pair = blockIdx.x >> 1;
    const int ks = blockIdx.x & 1;
    const int b0 = pair * 2;
    const int t = threadIdx.x;
    const int lane = t & 63, wc = t >> 6;
    const int r16 = lane & 15, slot = lane >> 4;

    __shared__ alignas(16) char xs[51200];

    // 5 row-tiles cover grow = 0..79; grow = img*36 + hw for grow < 72
    int aimg[5], lc[5];
    #pragma unroll
    for (int mt = 0; mt < 5; ++mt) {
        int grow = mt * 16 + r16;
        int img = (grow >= 36 && grow < 72) ? 1 : 0;
        int hw = (grow < 72) ? (grow - 36 * img) : 0;
        int h = hw / 6, w = hw - h * 6;
        aimg[mt] = img * 25600;
        lc[mt] = 40 * h + w;
    }

    float4v acc[5][4];
    #pragma unroll
    for (int mt = 0; mt < 5; ++mt)
        #pragma unroll
        for (int nt = 0; nt < 4; ++nt)
            acc[mt][nt] = (float4v){0.f, 0.f, 0.f, 0.f};

    for (int i4 = 0; i4 < 4; ++i4) {
        const int icc = ks * 4 + i4;
        __syncthreads();                       // waves done reading xs
        stage_x(xt, xs, b0, icc, t);
        __syncthreads();                       // stage complete (vmcnt drained)

        const __hip_bfloat16* bp = Bw2 + ((size_t)icc * 4 + wc) * 2048 + lane * 8;

        #pragma unroll 3
        for (int kidx = 0; kidx < 81; ++kidx) {
            int ky = kidx / 9, kx = kidx - ky * 9;
            int scalK = 20 * ky + 10 * (kx & 1) + (kx >> 1);
            short8v a[5];
            #pragma unroll
            for (int mt = 0; mt < 5; ++mt) {
                int pos = lc[mt] + scalK;
                int off = aimg[mt] + pos * 64 + (((slot ^ (pos >> 1)) & 3) << 4);
                a[mt] = *(const short8v*)(xs + off);
            }
            const __hip_bfloat16* bq = bp + (size_t)kidx * 65536;
            short8v bv[4];
            #pragma unroll
            for (int nt = 0; nt < 4; ++nt)
                bv[nt] = *(const short8v*)(bq + nt * 512);
            #pragma unroll
            for (int mt = 0; mt < 5; ++mt)
                #pragma unroll
                for (int nt = 0; nt < 4; ++nt)
                    acc[mt][nt] = __builtin_amdgcn_mfma_f32_16x16x32_bf16(a[mt], bv[nt], acc[mt][nt], 0, 0, 0);
        }
    }

    // epilogue: D row grow = mt*16 + slot*4 + i (36%4==0 -> blocks never
    // straddle an image boundary); col(oc) = r16. ks0 adds bias -> u0.
    float* uo = ks ? u1 : u0;
    #pragma unroll
    for (int mt = 0; mt < 5; ++mt) {
        int grow0 = mt * 16 + slot * 4;
        if (grow0 < 72) {
            int img = grow0 >= 36;
            int hwb = grow0 - 36 * img;
            const int b = b0 + img;
            #pragma unroll
            for (int nt = 0; nt < 4; ++nt) {
                int oc = wc * 64 + nt * 16 + r16;
                float pb = ks ? 0.f : pcb[oc];
                float4v v = acc[mt][nt];
                v.x += pb; v.y += pb; v.z += pb; v.w += pb;
                *(float4v*)(uo + (size_t)b * 9216 + oc * 36 + hwb) = v;
            }
        }
    }
}

// ---------------------------------------------------------------------------
// squash groups of 8: u0 <- squash(u0 + u1)
// ---------------------------------------------------------------------------
__global__ void k_squash_u2(float* __restrict__ u0, const float* __restrict__ u1,
                            int ngroups)
{
    int g = blockIdx.x * blockDim.x + threadIdx.x;
    if (g >= ngroups) return;
    float4v* p0 = (float4v*)(u0 + (size_t)g * 8);
    const float4v* p1 = (const float4v*)(u1 + (size_t)g * 8);
    float4v a = p0[0] + p1[0], c = p0[1] + p1[1];
    float sq = a.x * a.x + a.y * a.y + a.z * a.z + a.w * a.w
             + c.x * c.x + c.y * c.y + c.z * c.z + c.w * c.w;
    float scale = (sq / (1.f + sq)) / sqrtf(sq + EPSF);
    a *= scale; c *= scale;
    p0[0] = a; p0[1] = c;
}

// ---------------------------------------------------------------------------
// routing: grid 576 = 144 rc (8 W-rows) x 4 bc (128 images); 256 thr.
// Thread = (oq, img) handles TWO images; W LDS-reads shared by both.
// ---------------------------------------------------------------------------
__global__ __launch_bounds__(256, 2) void k_route3(const float* __restrict__ u,
                                                   const float* __restrict__ W,
                                                   const float* __restrict__ vsum,
                                                   float* __restrict__ spart, int iter)
{
    const int bid = blockIdx.x;
    const int rc = bid % 144;
    const int bc = bid / 144;          // 0..3
    const int r0 = rc * 8;
    const int b0 = bc * 128;
    const int t = threadIdx.x;
    const int oq = t & 3;
    const int img = t >> 2;            // 0..63
    const int bA = b0 + img, bB = bA + 64;

    __shared__ alignas(16) float Wl[10240];     // 40KB: 8 rows x 320 f4, swizzled
    __shared__ alignas(16) float ul[128 * 68];  // 34.8KB: u tile, stride 68

    #pragma unroll
    for (int k = 0; k < 10; ++k) {
        int e = t + k * 256;
        int rr = e / 320, rest = e - rr * 320;
        float4v val = *(const float4v*)(W + (size_t)(r0 + rr) * 1280 + rest * 4);
        int es = e ^ ((e >> 3) & 3);
        *(float4v*)(Wl + es * 4) = val;
    }
    #pragma unroll
    for (int k = 0; k < 8; ++k) {
        int e = t + k * 256;           // 0..2047
        int im = e >> 4, f4 = e & 15;
        float4v val = *(const float4v*)(u + (size_t)(b0 + im) * 9216 + rc * 64 + f4 * 4);
        *(float4v*)(ul + im * 68 + f4 * 4) = val;
    }
    __syncthreads();

    float4v accA[10], accB[10];
    #pragma unroll
    for (int j = 0; j < 10; ++j) {
        accA[j] = (float4v){0.f, 0.f, 0.f, 0.f};
        accB[j] = (float4v){0.f, 0.f, 0.f, 0.f};
    }

    const float* upA = ul + img * 68;
    const float* upB = ul + (img + 64) * 68;

    for (int r = 0; r < 8; ++r) {
        float4v uA0 = *(const float4v*)(upA + r * 8);
        float4v uA1 = *(const float4v*)(upA + r * 8 + 4);
        float4v uB0 = *(const float4v*)(upB + r * 8);
        float4v uB1 = *(const float4v*)(upB + r * 8 + 4);
        float4v uhA[10], uhB[10];
        #pragma unroll
        for (int j = 0; j < 10; ++j) {
            #pragma unroll
            for (int oo = 0; oo < 4; ++oo) {
                int un = r * 320 + j * 32 + oq * 8 + oo * 2;
                int i0 = un ^ oq;      // (un>>3)&3 == oq here
                int i1 = i0 ^ 1;
                float4v wlo = *(const float4v*)(Wl + i0 * 4);
                float4v whi = *(const float4v*)(Wl + i1 * 4);
                uhA[j][oo] = wlo.x * uA0.x + wlo.y * uA0.y + wlo.z * uA0.z + wlo.w * uA0.w
                           + whi.x * uA1.x + whi.y * uA1.y + whi.z * uA1.z + whi.w * uA1.w;
                uhB[j][oo] = wlo.x * uB0.x + wlo.y * uB0.y + wlo.z * uB0.z + wlo.w * uB0.w
                           + whi.x * uB1.x + whi.y * uB1.y + whi.z * uB1.z + whi.w * uB1.w;
            }
        }
        if (iter > 0) {
            #pragma unroll 2
            for (int half = 0; half < 2; ++half) {
                const int b = half ? bB : bA;
                float4v* uh = half ? uhB : uhA;
                float4v* acc = half ? accB : accA;
                float q[10];
                #pragma unroll
                for (int j = 0; j < 10; ++j) {
                    float4v vj = *(const float4v*)(vsum + (size_t)b * 160 + j * 16 + oq * 4);
                    float qp = uh[j].x * vj.x + uh[j].y * vj.y
                             + uh[j].z * vj.z + uh[j].w * vj.w;
                    qp += __shfl_xor(qp, 1);
                    qp += __shfl_xor(qp, 2);
                    q[j] = qp;
                }
                float mx = q[0];
                #pragma unroll
                for (int j = 1; j < 10; ++j) mx = fmaxf(mx, q[j]);
                float ssum = 0.f;
                float c[10];
                #pragma unroll
                for (int j = 0; j < 10; ++j) { c[j] = __expf(q[j] - mx); ssum += c[j]; }
                float inv = 1.f / ssum;
                #pragma unroll
                for (int j = 0; j < 10; ++j) acc[j] += (c[j] * inv) * uh[j];
            }
        } else {
            #pragma unroll
            for (int j = 0; j < 10; ++j) {
                accA[j] += 0.1f * uhA[j];
                accB[j] += 0.1f * uhB[j];
            }
        }
    }

    float* dstA = spart + ((size_t)rc * 512 + bA) * 160 + oq * 4;
    float* dstB = spart + ((size_t)rc * 512 + bB) * 160 + oq * 4;
    #pragma unroll
    for (int j = 0; j < 10; ++j) {
        *(float4v*)(dstA + j * 16) = accA[j];
        *(float4v*)(dstB + j * 16) = accB[j];
    }
}

// ---------------------------------------------------------------------------
// finish: sum 144 partials -> squash -> v; vsum update; iter==2 writes outputs
// ---------------------------------------------------------------------------
__global__ void k_finish(const float* __restrict__ spart, float* __restrict__ vsum,
                         const int* __restrict__ label, float* __restrict__ obj,
                         float* __restrict__ yprob, float* __restrict__ masked, int iter)
{
    const int b = blockIdx.x, t = threadIdx.x;
    if (t < 160) {
        const float* sp = spart + (size_t)b * 160 + t;
        float sv = 0.f;
        #pragma unroll 8
        for (int rc = 0; rc < 144; ++rc)
            sv += sp[(size_t)rc * 81920];
        float sq = sv * sv;
        sq += __shfl_xor(sq, 1); sq += __shfl_xor(sq, 2);
        sq += __shfl_xor(sq, 4); sq += __shfl_xor(sq, 8);
        float v = sv * (sq / (1.f + sq)) / sqrtf(sq + EPSF);
        float pv = (iter > 0) ? vsum[b * 160 + t] : 0.f;
        vsum[b * 160 + t] = pv + v;
        if (iter == 2) {
            obj[b * 160 + t] = v;
            float vv = v * v;
            vv += __shfl_xor(vv, 1); vv += __shfl_xor(vv, 2);
            vv += __shfl_xor(vv, 4); vv += __shfl_xor(vv, 8);
            int j = t >> 4;
            if ((t & 15) == 0) yprob[b * 10 + j] = sqrtf(vv + EPSF);
            masked[b * 160 + t] = (label[b] == j) ? v : 0.f;
        }
    }
}

// ---------------------------------------------------------------------------
// decoder GEMM: C[m,n] = act(bias[n] + sum_k A[m,k]*Wt[n,k]); M=512.
// ---------------------------------------------------------------------------
__global__ void k_mlp(const float* __restrict__ A, const float* __restrict__ Wt,
                      const float* __restrict__ bias, float* __restrict__ C,
                      int N, int K, int act)
{
    const int m0 = blockIdx.x * 32;
    const int n0 = blockIdx.y * 32;
    const int t  = threadIdx.x;
    const int tn = t & 31, tg = t >> 5;
    __shared__ float As[32][33];
    __shared__ float Ws[32][33];
    float acc[4] = {0.f, 0.f, 0.f, 0.f};
    for (int k0 = 0; k0 < K; k0 += 32) {
        __syncthreads();
        for (int idx = t; idx < 1024; idx += 256) {
            int rr = idx >> 5, kk = idx & 31;
            As[rr][kk] = A[(size_t)(m0 + rr) * K + k0 + kk];
            int n = n0 + rr;
            Ws[rr][kk] = (n < N) ? Wt[(size_t)n * K + k0 + kk] : 0.f;
        }
        __syncthreads();
        #pragma unroll 8
        for (int kk = 0; kk < 32; ++kk) {
            float bv = Ws[tn][kk];
            #pragma unroll
            for (int i = 0; i < 4; ++i)
                acc[i] += As[tg * 4 + i][kk] * bv;
        }
    }
    int n = n0 + tn;
    if (n < N) {
        float bs = bias[n];
        #pragma unroll
        for (int i = 0; i < 4; ++i) {
            float vv = acc[i] + bs;
            vv = (act == 0) ? fmaxf(vv, 0.f) : 1.f / (1.f + expf(-vv));
            C[(size_t)(m0 + tg * 4 + i) * N + n] = vv;
        }
    }
}

// ---------------------------------------------------------------------------
extern "C" void kernel_launch(void* const* d_in, const int* in_sizes, int n_in,
                              void* d_out, int out_size, void* d_ws, size_t ws_size,
                              hipStream_t stream)
{
    const float* image  = (const float*)d_in[0];
    const int*   label  = (const int*)  d_in[1];
    const float* conv_w = (const float*)d_in[2];
    const float* conv_b = (const float*)d_in[3];
    const float* pc_w   = (const float*)d_in[4];
    const float* pc_b   = (const float*)d_in[5];
    const float* Wrt    = (const float*)d_in[6];
    const float* dw1 = (const float*)d_in[7];
    const float* db1 = (const float*)d_in[8];
    const float* dw2 = (const float*)d_in[9];
    const float* db2 = (const float*)d_in[10];
    const float* dw3 = (const float*)d_in[11];
    const float* db3 = (const float*)d_in[12];
    float* out = (float*)d_out;

    char* p = (char*)d_ws;
    __hip_bfloat16* xt  = (__hip_bfloat16*)p; p += 104857600;
    float* u      = (float*)p; p += 18874368;   // u0 (final u)
    float* u1     = (float*)p; p += 18874368;   // ks=1 partial
    __hip_bfloat16* Bw2 = (__hip_bfloat16*)p; p += 10616832;
    float* vsum   = (float*)p; p += 327680;
    float* masked = (float*)p; p += 327680;
    float* h1     = (float*)p; p += 1048576;
    float* h2     = (float*)p; p += 2097152;

    // spart [144][512][160] f32 (47.2 MB) aliases xt (dead after k_conv2,
    // fully rewritten by conv1 each launch -> deterministic across replays).
    float* spart = (float*)xt;

    float* obj   = out;            // [512,10,16,1]
    float* recon = out + 81920;    // [512,1,28,28]
    float* yprob = out + 483328;   // [512,10]

    k_bw2<<<256, 256, 0, stream>>>(pc_w, Bw2);
    k_conv1<<<512, 256, 0, stream>>>(image, conv_w, conv_b, xt);
    k_conv2<<<512, 256, 0, stream>>>(xt, Bw2, pc_b, u, u1);
    k_squash_u2<<<2304, 256, 0, stream>>>(u, u1, 589824);
    for (int it = 0; it < 3; ++it) {
        k_route3<<<576, 256, 0, stream>>>(u, Wrt, vsum, spart, it);
        k_finish<<<512, 192, 0, stream>>>(spart, vsum, label, obj, yprob, masked, it);
    }
    k_mlp<<<dim3(16, 16), 256, 0, stream>>>(masked, dw1, db1, h1, 512, 160, 0);
    k_mlp<<<dim3(16, 32), 256, 0, stream>>>(h1, dw2, db2, h2, 1024, 512, 0);
    k_mlp<<<dim3(16, 25), 256, 0, stream>>>(h2, dw3, db3, recon, 784, 1024, 1);
}

// Round 17
// 695.724 us; speedup vs baseline: 1.2537x; 1.0219x over previous
//
#include <hip/hip_runtime.h>
#include <hip/hip_bf16.h>

#define EPSF 1e-8f

typedef __attribute__((ext_vector_type(8))) short short8v;
typedef __attribute__((ext_vector_type(4))) float float4v;

static __device__ __forceinline__ unsigned short f2bf_bits(float x)
{
    return __builtin_bit_cast(unsigned short, __float2bfloat16(x));
}

// ---------------------------------------------------------------------------
// Bw2 transform: pc_w f32 [256oc][256ic][81k] -> coalesced per-wave chunks:
//   chunk_id = ((kidx*8+icc)*4+wc)*4+nt ; within chunk lane(slot*16+r16)*8+i
// ---------------------------------------------------------------------------
__global__ __launch_bounds__(256) void k_bw2(const float* __restrict__ pw,
                                             __hip_bfloat16* __restrict__ Bw2)
{
    const int oc = blockIdx.x;
    const int t = threadIdx.x;
    __shared__ unsigned short wl[20736];   // [ic][k] bf16 bits
    for (int i = t; i < 20736; i += 256)
        wl[i] = f2bf_bits(pw[(size_t)oc * 20736 + i]);
    __syncthreads();
    const int r16 = oc & 15, nt = (oc >> 4) & 3, wcq = oc >> 6;
    for (int e = t; e < 2592; e += 256) {
        const int kidx = e >> 5, icc = (e >> 2) & 7, slot = e & 3;
        short8v v;
        #pragma unroll
        for (int i = 0; i < 8; ++i)
            v[i] = (short)wl[(icc * 32 + slot * 8 + i) * 81 + kidx];
        const int chunk = ((kidx * 8 + icc) * 4 + wcq) * 4 + nt;
        *(short8v*)(Bw2 + (size_t)chunk * 512 + (slot * 16 + r16) * 8) = v;
    }
}

// ---------------------------------------------------------------------------
// conv1: image[512,1,28,28] * cw[256,1,9,9] + cb -> relu
//   -> x_t bf16 [b][icc=8][pos=400][64B unit, slot-XOR-permuted]
//   pos = h*20 + (w&1)*10 + (w>>1); unit byte: ((slot ^ ((pos>>1)&3))<<4)+ic8*2
// Rolling 9-row register window (h fully unrolled -> compile-time indices):
// each input row read ONCE per wg (420 ds_reads/thread vs 2700 naive).
// ---------------------------------------------------------------------------
__global__ __launch_bounds__(256) void k_conv1(const float* __restrict__ img,
                                               const float* __restrict__ cw,
                                               const float* __restrict__ cb,
                                               __hip_bfloat16* __restrict__ xt)
{
    const int b = blockIdx.x;
    const int c = threadIdx.x;
    __shared__ float simg[784];
    for (int i = c; i < 784; i += 256) simg[i] = img[b * 784 + i];
    float wreg[81];
    const float* wp = cw + c * 81;
    #pragma unroll
    for (int k = 0; k < 81; ++k) wreg[k] = wp[k];
    const float bias = cb[c];
    __syncthreads();

    const int icc = c >> 5, slot = (c >> 3) & 3, ic8 = c & 7;
    char* xbase = (char*)xt + ((size_t)b * 8 + icc) * 25600;

    for (int wg = 0; wg < 5; ++wg) {
        const float* base = &simg[wg * 4];     // row r at base + r*28 (16B-aligned)
        float win[9][12];
        #pragma unroll
        for (int r = 0; r < 8; ++r) {
            const float4v* rp = (const float4v*)(base + r * 28);
            float4v A = rp[0], B = rp[1], C = rp[2];
            win[r][0] = A.x; win[r][1] = A.y; win[r][2]  = A.z; win[r][3]  = A.w;
            win[r][4] = B.x; win[r][5] = B.y; win[r][6]  = B.z; win[r][7]  = B.w;
            win[r][8] = C.x; win[r][9] = C.y; win[r][10] = C.z; win[r][11] = C.w;
        }
        #pragma unroll
        for (int h = 0; h < 20; ++h) {
            {   // load row h+8 into slot (h+8)%9
                const int ws = (h + 8) % 9;
                const float4v* rp = (const float4v*)(base + (h + 8) * 28);
                float4v A = rp[0], B = rp[1], C = rp[2];
                win[ws][0] = A.x; win[ws][1] = A.y; win[ws][2]  = A.z; win[ws][3]  = A.w;
                win[ws][4] = B.x; win[ws][5] = B.y; win[ws][6]  = B.z; win[ws][7]  = B.w;
                win[ws][8] = C.x; win[ws][9] = C.y; win[ws][10] = C.z; win[ws][11] = C.w;
            }
            float acc[4] = {bias, bias, bias, bias};
            #pragma unroll
            for (int ky = 0; ky < 9; ++ky) {
                const int rs = (h + ky) % 9;
                #pragma unroll
                for (int kx = 0; kx < 9; ++kx) {
                    const float wv = wreg[ky * 9 + kx];
                    #pragma unroll
                    for (int i = 0; i < 4; ++i)
                        acc[i] = fmaf(win[rs][kx + i], wv, acc[i]);
                }
            }
            #pragma unroll
            for (int i = 0; i < 4; ++i) {
                int w = wg * 4 + i;
                float av = fmaxf(acc[i], 0.f);
                int pos = h * 20 + (w & 1) * 10 + (w >> 1);
                int off = pos * 64 + ((slot ^ ((pos >> 1) & 3)) << 4) + ic8 * 2;
                *(unsigned short*)(xbase + off) = f2bf_bits(av);
            }
        }
    }
}

// ---------------------------------------------------------------------------
// async stage of one icc-chunk (2 images, 51200 B) into LDS; 256 threads.
// ---------------------------------------------------------------------------
__device__ __forceinline__ void stage_x(const __hip_bfloat16* __restrict__ xt,
                                        char* dst, int b0, int icc, int t)
{
    const __hip_bfloat16* base0 = xt + ((size_t)(b0    ) * 8 + icc) * 12800;
    const __hip_bfloat16* base1 = xt + ((size_t)(b0 + 1) * 8 + icc) * 12800;
    #pragma unroll
    for (int k = 0; k < 12; ++k) {
        const int unit = t + k * 256;
        const __hip_bfloat16* gp = (unit < 1600) ? (base0 + unit * 8)
                                                 : (base1 + (unit - 1600) * 8);
        __builtin_amdgcn_global_load_lds(
            (const __attribute__((address_space(1))) unsigned int*)gp,
            (__attribute__((address_space(3))) unsigned int*)(dst + unit * 16),
            16, 0, 0);
    }
    if (t < 128) {
        const int unit = 3072 + t;
        const __hip_bfloat16* gp = base1 + (unit - 1600) * 8;
        __builtin_amdgcn_global_load_lds(
            (const __attribute__((address_space(1))) unsigned int*)gp,
            (__attribute__((address_space(3))) unsigned int*)(dst + unit * 16),
            16, 0, 0);
    }
}

// ---------------------------------------------------------------------------
// conv2 via MFMA, packed-M + K-split: grid 512 = 256 pairs x 2 ks (4 icc each).
// 256 thr = 4 waves (wc). Rows of BOTH images packed into 5 shared 16-row
// tiles -> 20 MFMA per 4KB B-load; K-split gives 2 blocks/CU (8 waves/CU)
// while each wave issues only 1.3MB of B. Partials -> u0 (ks0,+bias) / u1.
// ---------------------------------------------------------------------------
__global__ __launch_bounds__(256, 2) void k_conv2(const __hip_bfloat16* __restrict__ xt,
                                                  const __hip_bfloat16* __restrict__ Bw2,
                                                  const float* __restrict__ pcb,
                                                  float* __restrict__ u0,
                                                  float* __restrict__ u1)
{
    const int pair = blockIdx.x >> 1;
    const int ks = blockIdx.x & 1;
    const int b0 = pair * 2;
    const int t = threadIdx.x;
    const int lane = t & 63, wc = t >> 6;
    const int r16 = lane & 15, slot = lane >> 4;

    __shared__ alignas(16) char xs[51200];

    // 5 row-tiles cover grow = 0..79; grow = img*36 + hw for grow < 72
    int aimg[5], lc[5];
    #pragma unroll
    for (int mt = 0; mt < 5; ++mt) {
        int grow = mt * 16 + r16;
        int img = (grow >= 36 && grow < 72) ? 1 : 0;
        int hw = (grow < 72) ? (grow - 36 * img) : 0;
        int h = hw / 6, w = hw - h * 6;
        aimg[mt] = img * 25600;
        lc[mt] = 40 * h + w;
    }

    float4v acc[5][4];
    #pragma unroll
    for (int mt = 0; mt < 5; ++mt)
        #pragma unroll
        for (int nt = 0; nt < 4; ++nt)
            acc[mt][nt] = (float4v){0.f, 0.f, 0.f, 0.f};

    for (int i4 = 0; i4 < 4; ++i4) {
        const int icc = ks * 4 + i4;
        __syncthreads();                       // waves done reading xs
        stage_x(xt, xs, b0, icc, t);
        __syncthreads();                       // stage complete (vmcnt drained)

        const __hip_bfloat16* bp = Bw2 + ((size_t)icc * 4 + wc) * 2048 + lane * 8;

        #pragma unroll 3
        for (int kidx = 0; kidx < 81; ++kidx) {
            int ky = kidx / 9, kx = kidx - ky * 9;
            int scalK = 20 * ky + 10 * (kx & 1) + (kx >> 1);
            short8v a[5];
            #pragma unroll
            for (int mt = 0; mt < 5; ++mt) {
                int pos = lc[mt] + scalK;
                int off = aimg[mt] + pos * 64 + (((slot ^ (pos >> 1)) & 3) << 4);
                a[mt] = *(const short8v*)(xs + off);
            }
            const __hip_bfloat16* bq = bp + (size_t)kidx * 65536;
            short8v bv[4];
            #pragma unroll
            for (int nt = 0; nt < 4; ++nt)
                bv[nt] = *(const short8v*)(bq + nt * 512);
            #pragma unroll
            for (int mt = 0; mt < 5; ++mt)
                #pragma unroll
                for (int nt = 0; nt < 4; ++nt)
                    acc[mt][nt] = __builtin_amdgcn_mfma_f32_16x16x32_bf16(a[mt], bv[nt], acc[mt][nt], 0, 0, 0);
        }
    }

    // epilogue: D row grow = mt*16 + slot*4 + i (36%4==0 -> blocks never
    // straddle an image boundary); col(oc) = r16. ks0 adds bias -> u0.
    float* uo = ks ? u1 : u0;
    #pragma unroll
    for (int mt = 0; mt < 5; ++mt) {
        int grow0 = mt * 16 + slot * 4;
        if (grow0 < 72) {
            int img = grow0 >= 36;
            int hwb = grow0 - 36 * img;
            const int b = b0 + img;
            #pragma unroll
            for (int nt = 0; nt < 4; ++nt) {
                int oc = wc * 64 + nt * 16 + r16;
                float pb = ks ? 0.f : pcb[oc];
                float4v v = acc[mt][nt];
                v.x += pb; v.y += pb; v.z += pb; v.w += pb;
                *(float4v*)(uo + (size_t)b * 9216 + oc * 36 + hwb) = v;
            }
        }
    }
}

// ---------------------------------------------------------------------------
// squash groups of 8: u0 <- squash(u0 + u1)
// ---------------------------------------------------------------------------
__global__ void k_squash_u2(float* __restrict__ u0, const float* __restrict__ u1,
                            int ngroups)
{
    int g = blockIdx.x * blockDim.x + threadIdx.x;
    if (g >= ngroups) return;
    float4v* p0 = (float4v*)(u0 + (size_t)g * 8);
    const float4v* p1 = (const float4v*)(u1 + (size_t)g * 8);
    float4v a = p0[0] + p1[0], c = p0[1] + p1[1];
    float sq = a.x * a.x + a.y * a.y + a.z * a.z + a.w * a.w
             + c.x * c.x + c.y * c.y + c.z * c.z + c.w * c.w;
    float scale = (sq / (1.f + sq)) / sqrtf(sq + EPSF);
    a *= scale; c *= scale;
    p0[0] = a; p0[1] = c;
}

// ---------------------------------------------------------------------------
// routing: grid 576 = 144 rc (8 W-rows) x 4 bc (128 images); 256 thr.
// Thread = (oq, img) handles TWO images; W LDS-reads shared by both.
// ---------------------------------------------------------------------------
__global__ __launch_bounds__(256, 2) void k_route3(const float* __restrict__ u,
                                                   const float* __restrict__ W,
                                                   const float* __restrict__ vsum,
                                                   float* __restrict__ spart, int iter)
{
    const int bid = blockIdx.x;
    const int rc = bid % 144;
    const int bc = bid / 144;          // 0..3
    const int r0 = rc * 8;
    const int b0 = bc * 128;
    const int t = threadIdx.x;
    const int oq = t & 3;
    const int img = t >> 2;            // 0..63
    const int bA = b0 + img, bB = bA + 64;

    __shared__ alignas(16) float Wl[10240];     // 40KB: 8 rows x 320 f4, swizzled
    __shared__ alignas(16) float ul[128 * 68];  // 34.8KB: u tile, stride 68

    #pragma unroll
    for (int k = 0; k < 10; ++k) {
        int e = t + k * 256;
        int rr = e / 320, rest = e - rr * 320;
        float4v val = *(const float4v*)(W + (size_t)(r0 + rr) * 1280 + rest * 4);
        int es = e ^ ((e >> 3) & 3);
        *(float4v*)(Wl + es * 4) = val;
    }
    #pragma unroll
    for (int k = 0; k < 8; ++k) {
        int e = t + k * 256;           // 0..2047
        int im = e >> 4, f4 = e & 15;
        float4v val = *(const float4v*)(u + (size_t)(b0 + im) * 9216 + rc * 64 + f4 * 4);
        *(float4v*)(ul + im * 68 + f4 * 4) = val;
    }
    __syncthreads();

    float4v accA[10], accB[10];
    #pragma unroll
    for (int j = 0; j < 10; ++j) {
        accA[j] = (float4v){0.f, 0.f, 0.f, 0.f};
        accB[j] = (float4v){0.f, 0.f, 0.f, 0.f};
    }

    const float* upA = ul + img * 68;
    const float* upB = ul + (img + 64) * 68;

    for (int r = 0; r < 8; ++r) {
        float4v uA0 = *(const float4v*)(upA + r * 8);
        float4v uA1 = *(const float4v*)(upA + r * 8 + 4);
        float4v uB0 = *(const float4v*)(upB + r * 8);
        float4v uB1 = *(const float4v*)(upB + r * 8 + 4);
        float4v uhA[10], uhB[10];
        #pragma unroll
        for (int j = 0; j < 10; ++j) {
            #pragma unroll
            for (int oo = 0; oo < 4; ++oo) {
                int un = r * 320 + j * 32 + oq * 8 + oo * 2;
                int i0 = un ^ oq;      // (un>>3)&3 == oq here
                int i1 = i0 ^ 1;
                float4v wlo = *(const float4v*)(Wl + i0 * 4);
                float4v whi = *(const float4v*)(Wl + i1 * 4);
                uhA[j][oo] = wlo.x * uA0.x + wlo.y * uA0.y + wlo.z * uA0.z + wlo.w * uA0.w
                           + whi.x * uA1.x + whi.y * uA1.y + whi.z * uA1.z + whi.w * uA1.w;
                uhB[j][oo] = wlo.x * uB0.x + wlo.y * uB0.y + wlo.z * uB0.z + wlo.w * uB0.w
                           + whi.x * uB1.x + whi.y * uB1.y + whi.z * uB1.z + whi.w * uB1.w;
            }
        }
        if (iter > 0) {
            #pragma unroll 2
            for (int half = 0; half < 2; ++half) {
                const int b = half ? bB : bA;
                float4v* uh = half ? uhB : uhA;
                float4v* acc = half ? accB : accA;
                float q[10];
                #pragma unroll
                for (int j = 0; j < 10; ++j) {
                    float4v vj = *(const float4v*)(vsum + (size_t)b * 160 + j * 16 + oq * 4);
                    float qp = uh[j].x * vj.x + uh[j].y * vj.y
                             + uh[j].z * vj.z + uh[j].w * vj.w;
                    qp += __shfl_xor(qp, 1);
                    qp += __shfl_xor(qp, 2);
                    q[j] = qp;
                }
                float mx = q[0];
                #pragma unroll
                for (int j = 1; j < 10; ++j) mx = fmaxf(mx, q[j]);
                float ssum = 0.f;
                float c[10];
                #pragma unroll
                for (int j = 0; j < 10; ++j) { c[j] = __expf(q[j] - mx); ssum += c[j]; }
                float inv = 1.f / ssum;
                #pragma unroll
                for (int j = 0; j < 10; ++j) acc[j] += (c[j] * inv) * uh[j];
            }
        } else {
            #pragma unroll
            for (int j = 0; j < 10; ++j) {
                accA[j] += 0.1f * uhA[j];
                accB[j] += 0.1f * uhB[j];
            }
        }
    }

    float* dstA = spart + ((size_t)rc * 512 + bA) * 160 + oq * 4;
    float* dstB = spart + ((size_t)rc * 512 + bB) * 160 + oq * 4;
    #pragma unroll
    for (int j = 0; j < 10; ++j) {
        *(float4v*)(dstA + j * 16) = accA[j];
        *(float4v*)(dstB + j * 16) = accB[j];
    }
}

// ---------------------------------------------------------------------------
// finish: sum 144 partials -> squash -> v; vsum update; iter==2 writes outputs
// ---------------------------------------------------------------------------
__global__ void k_finish(const float* __restrict__ spart, float* __restrict__ vsum,
                         const int* __restrict__ label, float* __restrict__ obj,
                         float* __restrict__ yprob, float* __restrict__ masked, int iter)
{
    const int b = blockIdx.x, t = threadIdx.x;
    if (t < 160) {
        const float* sp = spart + (size_t)b * 160 + t;
        float sv = 0.f;
        #pragma unroll 8
        for (int rc = 0; rc < 144; ++rc)
            sv += sp[(size_t)rc * 81920];
        float sq = sv * sv;
        sq += __shfl_xor(sq, 1); sq += __shfl_xor(sq, 2);
        sq += __shfl_xor(sq, 4); sq += __shfl_xor(sq, 8);
        float v = sv * (sq / (1.f + sq)) / sqrtf(sq + EPSF);
        float pv = (iter > 0) ? vsum[b * 160 + t] : 0.f;
        vsum[b * 160 + t] = pv + v;
        if (iter == 2) {
            obj[b * 160 + t] = v;
            float vv = v * v;
            vv += __shfl_xor(vv, 1); vv += __shfl_xor(vv, 2);
            vv += __shfl_xor(vv, 4); vv += __shfl_xor(vv, 8);
            int j = t >> 4;
            if ((t & 15) == 0) yprob[b * 10 + j] = sqrtf(vv + EPSF);
            masked[b * 160 + t] = (label[b] == j) ? v : 0.f;
        }
    }
}

// ---------------------------------------------------------------------------
// decoder GEMM: C[m,n] = act(bias[n] + sum_k A[m,k]*Wt[n,k]); M=512.
// ---------------------------------------------------------------------------
__global__ void k_mlp(const float* __restrict__ A, const float* __restrict__ Wt,
                      const float* __restrict__ bias, float* __restrict__ C,
                      int N, int K, int act)
{
    const int m0 = blockIdx.x * 32;
    const int n0 = blockIdx.y * 32;
    const int t  = threadIdx.x;
    const int tn = t & 31, tg = t >> 5;
    __shared__ float As[32][33];
    __shared__ float Ws[32][33];
    float acc[4] = {0.f, 0.f, 0.f, 0.f};
    for (int k0 = 0; k0 < K; k0 += 32) {
        __syncthreads();
        for (int idx = t; idx < 1024; idx += 256) {
            int rr = idx >> 5, kk = idx & 31;
            As[rr][kk] = A[(size_t)(m0 + rr) * K + k0 + kk];
            int n = n0 + rr;
            Ws[rr][kk] = (n < N) ? Wt[(size_t)n * K + k0 + kk] : 0.f;
        }
        __syncthreads();
        #pragma unroll 8
        for (int kk = 0; kk < 32; ++kk) {
            float bv = Ws[tn][kk];
            #pragma unroll
            for (int i = 0; i < 4; ++i)
                acc[i] += As[tg * 4 + i][kk] * bv;
        }
    }
    int n = n0 + tn;
    if (n < N) {
        float bs = bias[n];
        #pragma unroll
        for (int i = 0; i < 4; ++i) {
            float vv = acc[i] + bs;
            vv = (act == 0) ? fmaxf(vv, 0.f) : 1.f / (1.f + expf(-vv));
            C[(size_t)(m0 + tg * 4 + i) * N + n] = vv;
        }
    }
}

// ---------------------------------------------------------------------------
extern "C" void kernel_launch(void* const* d_in, const int* in_sizes, int n_in,
                              void* d_out, int out_size, void* d_ws, size_t ws_size,
                              hipStream_t stream)
{
    const float* image  = (const float*)d_in[0];
    const int*   label  = (const int*)  d_in[1];
    const float* conv_w = (const float*)d_in[2];
    const float* conv_b = (const float*)d_in[3];
    const float* pc_w   = (const float*)d_in[4];
    const float* pc_b   = (const float*)d_in[5];
    const float* Wrt    = (const float*)d_in[6];
    const float* dw1 = (const float*)d_in[7];
    const float* db1 = (const float*)d_in[8];
    const float* dw2 = (const float*)d_in[9];
    const float* db2 = (const float*)d_in[10];
    const float* dw3 = (const float*)d_in[11];
    const float* db3 = (const float*)d_in[12];
    float* out = (float*)d_out;

    char* p = (char*)d_ws;
    __hip_bfloat16* xt  = (__hip_bfloat16*)p; p += 104857600;
    float* u      = (float*)p; p += 18874368;   // u0 (final u)
    float* u1     = (float*)p; p += 18874368;   // ks=1 partial
    __hip_bfloat16* Bw2 = (__hip_bfloat16*)p; p += 10616832;
    float* vsum   = (float*)p; p += 327680;
    float* masked = (float*)p; p += 327680;
    float* h1     = (float*)p; p += 1048576;
    float* h2     = (float*)p; p += 2097152;

    // spart [144][512][160] f32 (47.2 MB) aliases xt (dead after k_conv2,
    // fully rewritten by conv1 each launch -> deterministic across replays).
    float* spart = (float*)xt;

    float* obj   = out;            // [512,10,16,1]
    float* recon = out + 81920;    // [512,1,28,28]
    float* yprob = out + 483328;   // [512,10]

    k_bw2<<<256, 256, 0, stream>>>(pc_w, Bw2);
    k_conv1<<<512, 256, 0, stream>>>(image, conv_w, conv_b, xt);
    k_conv2<<<512, 256, 0, stream>>>(xt, Bw2, pc_b, u, u1);
    k_squash_u2<<<2304, 256, 0, stream>>>(u, u1, 589824);
    for (int it = 0; it < 3; ++it) {
        k_route3<<<576, 256, 0, stream>>>(u, Wrt, vsum, spart, it);
        k_finish<<<512, 192, 0, stream>>>(spart, vsum, label, obj, yprob, masked, it);
    }
    k_mlp<<<dim3(16, 16), 256, 0, stream>>>(masked, dw1, db1, h1, 512, 160, 0);
    k_mlp<<<dim3(16, 32), 256, 0, stream>>>(h1, dw2, db2, h2, 1024, 512, 0);
    k_mlp<<<dim3(16, 25), 256, 0, stream>>>(h2, dw3, db3, recon, 784, 1024, 1);
}

// Round 18
// 693.392 us; speedup vs baseline: 1.2579x; 1.0034x over previous
//
#include <hip/hip_runtime.h>
#include <hip/hip_bf16.h>

#define EPSF 1e-8f

typedef __attribute__((ext_vector_type(8))) short short8v;
typedef __attribute__((ext_vector_type(4))) float float4v;

static __device__ __forceinline__ unsigned short f2bf_bits(float x)
{
    return __builtin_bit_cast(unsigned short, __float2bfloat16(x));
}

// ---------------------------------------------------------------------------
// Bw2 transform: pc_w f32 [256oc][256ic][81k] -> coalesced per-wave chunks:
//   chunk_id = ((kidx*8+icc)*4+wc)*4+nt ; within chunk lane(slot*16+r16)*8+i
// ---------------------------------------------------------------------------
__global__ __launch_bounds__(256) void k_bw2(const float* __restrict__ pw,
                                             __hip_bfloat16* __restrict__ Bw2)
{
    const int oc = blockIdx.x;
    const int t = threadIdx.x;
    __shared__ unsigned short wl[20736];   // [ic][k] bf16 bits
    for (int i = t; i < 20736; i += 256)
        wl[i] = f2bf_bits(pw[(size_t)oc * 20736 + i]);
    __syncthreads();
    const int r16 = oc & 15, nt = (oc >> 4) & 3, wcq = oc >> 6;
    for (int e = t; e < 2592; e += 256) {
        const int kidx = e >> 5, icc = (e >> 2) & 7, slot = e & 3;
        short8v v;
        #pragma unroll
        for (int i = 0; i < 8; ++i)
            v[i] = (short)wl[(icc * 32 + slot * 8 + i) * 81 + kidx];
        const int chunk = ((kidx * 8 + icc) * 4 + wcq) * 4 + nt;
        *(short8v*)(Bw2 + (size_t)chunk * 512 + (slot * 16 + r16) * 8) = v;
    }
}

// ---------------------------------------------------------------------------
// conv1: image[512,1,28,28] * cw[256,1,9,9] + cb -> relu
//   -> x_t bf16 [b][icc=8][pos=400][64B unit, slot-XOR-permuted]
// Rolling 9-row register window (h fully unrolled -> compile-time indices).
// ---------------------------------------------------------------------------
__global__ __launch_bounds__(256) void k_conv1(const float* __restrict__ img,
                                               const float* __restrict__ cw,
                                               const float* __restrict__ cb,
                                               __hip_bfloat16* __restrict__ xt)
{
    const int b = blockIdx.x;
    const int c = threadIdx.x;
    __shared__ float simg[784];
    for (int i = c; i < 784; i += 256) simg[i] = img[b * 784 + i];
    float wreg[81];
    const float* wp = cw + c * 81;
    #pragma unroll
    for (int k = 0; k < 81; ++k) wreg[k] = wp[k];
    const float bias = cb[c];
    __syncthreads();

    const int icc = c >> 5, slot = (c >> 3) & 3, ic8 = c & 7;
    char* xbase = (char*)xt + ((size_t)b * 8 + icc) * 25600;

    for (int wg = 0; wg < 5; ++wg) {
        const float* base = &simg[wg * 4];
        float win[9][12];
        #pragma unroll
        for (int r = 0; r < 8; ++r) {
            const float4v* rp = (const float4v*)(base + r * 28);
            float4v A = rp[0], B = rp[1], C = rp[2];
            win[r][0] = A.x; win[r][1] = A.y; win[r][2]  = A.z; win[r][3]  = A.w;
            win[r][4] = B.x; win[r][5] = B.y; win[r][6]  = B.z; win[r][7]  = B.w;
            win[r][8] = C.x; win[r][9] = C.y; win[r][10] = C.z; win[r][11] = C.w;
        }
        #pragma unroll
        for (int h = 0; h < 20; ++h) {
            {
                const int ws = (h + 8) % 9;
                const float4v* rp = (const float4v*)(base + (h + 8) * 28);
                float4v A = rp[0], B = rp[1], C = rp[2];
                win[ws][0] = A.x; win[ws][1] = A.y; win[ws][2]  = A.z; win[ws][3]  = A.w;
                win[ws][4] = B.x; win[ws][5] = B.y; win[ws][6]  = B.z; win[ws][7]  = B.w;
                win[ws][8] = C.x; win[ws][9] = C.y; win[ws][10] = C.z; win[ws][11] = C.w;
            }
            float acc[4] = {bias, bias, bias, bias};
            #pragma unroll
            for (int ky = 0; ky < 9; ++ky) {
                const int rs = (h + ky) % 9;
                #pragma unroll
                for (int kx = 0; kx < 9; ++kx) {
                    const float wv = wreg[ky * 9 + kx];
                    #pragma unroll
                    for (int i = 0; i < 4; ++i)
                        acc[i] = fmaf(win[rs][kx + i], wv, acc[i]);
                }
            }
            #pragma unroll
            for (int i = 0; i < 4; ++i) {
                int w = wg * 4 + i;
                float av = fmaxf(acc[i], 0.f);
                int pos = h * 20 + (w & 1) * 10 + (w >> 1);
                int off = pos * 64 + ((slot ^ ((pos >> 1) & 3)) << 4) + ic8 * 2;
                *(unsigned short*)(xbase + off) = f2bf_bits(av);
            }
        }
    }
}

// ---------------------------------------------------------------------------
// async stage of one icc-chunk (2 images, 51200 B) into LDS; 256 threads.
// ---------------------------------------------------------------------------
__device__ __forceinline__ void stage_x(const __hip_bfloat16* __restrict__ xt,
                                        char* dst, int b0, int icc, int t)
{
    const __hip_bfloat16* base0 = xt + ((size_t)(b0    ) * 8 + icc) * 12800;
    const __hip_bfloat16* base1 = xt + ((size_t)(b0 + 1) * 8 + icc) * 12800;
    #pragma unroll
    for (int k = 0; k < 12; ++k) {
        const int unit = t + k * 256;
        const __hip_bfloat16* gp = (unit < 1600) ? (base0 + unit * 8)
                                                 : (base1 + (unit - 1600) * 8);
        __builtin_amdgcn_global_load_lds(
            (const __attribute__((address_space(1))) unsigned int*)gp,
            (__attribute__((address_space(3))) unsigned int*)(dst + unit * 16),
            16, 0, 0);
    }
    if (t < 128) {
        const int unit = 3072 + t;
        const __hip_bfloat16* gp = base1 + (unit - 1600) * 8;
        __builtin_amdgcn_global_load_lds(
            (const __attribute__((address_space(1))) unsigned int*)gp,
            (__attribute__((address_space(3))) unsigned int*)(dst + unit * 16),
            16, 0, 0);
    }
}

// ---------------------------------------------------------------------------
// conv2 via MFMA, packed-M + K-split: grid 512 = 256 pairs x 2 ks (4 icc each).
// 256 thr = 4 waves (wc). Rows of BOTH images packed into 5 shared 16-row
// tiles -> 20 MFMA per 4KB B-load. Partials -> u0 (ks0,+bias) / u1.
// ---------------------------------------------------------------------------
__global__ __launch_bounds__(256, 2) void k_conv2(const __hip_bfloat16* __restrict__ xt,
                                                  const __hip_bfloat16* __restrict__ Bw2,
                                                  const float* __restrict__ pcb,
                                                  float* __restrict__ u0,
                                                  float* __restrict__ u1)
{
    const int pair = blockIdx.x >> 1;
    const int ks = blockIdx.x & 1;
    const int b0 = pair * 2;
    const int t = threadIdx.x;
    const int lane = t & 63, wc = t >> 6;
    const int r16 = lane & 15, slot = lane >> 4;

    __shared__ alignas(16) char xs[51200];

    int aimg[5], lc[5];
    #pragma unroll
    for (int mt = 0; mt < 5; ++mt) {
        int grow = mt * 16 + r16;
        int img = (grow >= 36 && grow < 72) ? 1 : 0;
        int hw = (grow < 72) ? (grow - 36 * img) : 0;
        int h = hw / 6, w = hw - h * 6;
        aimg[mt] = img * 25600;
        lc[mt] = 40 * h + w;
    }

    float4v acc[5][4];
    #pragma unroll
    for (int mt = 0; mt < 5; ++mt)
        #pragma unroll
        for (int nt = 0; nt < 4; ++nt)
            acc[mt][nt] = (float4v){0.f, 0.f, 0.f, 0.f};

    for (int i4 = 0; i4 < 4; ++i4) {
        const int icc = ks * 4 + i4;
        __syncthreads();
        stage_x(xt, xs, b0, icc, t);
        __syncthreads();

        const __hip_bfloat16* bp = Bw2 + ((size_t)icc * 4 + wc) * 2048 + lane * 8;

        #pragma unroll 3
        for (int kidx = 0; kidx < 81; ++kidx) {
            int ky = kidx / 9, kx = kidx - ky * 9;
            int scalK = 20 * ky + 10 * (kx & 1) + (kx >> 1);
            short8v a[5];
            #pragma unroll
            for (int mt = 0; mt < 5; ++mt) {
                int pos = lc[mt] + scalK;
                int off = aimg[mt] + pos * 64 + (((slot ^ (pos >> 1)) & 3) << 4);
                a[mt] = *(const short8v*)(xs + off);
            }
            const __hip_bfloat16* bq = bp + (size_t)kidx * 65536;
            short8v bv[4];
            #pragma unroll
            for (int nt = 0; nt < 4; ++nt)
                bv[nt] = *(const short8v*)(bq + nt * 512);
            #pragma unroll
            for (int mt = 0; mt < 5; ++mt)
                #pragma unroll
                for (int nt = 0; nt < 4; ++nt)
                    acc[mt][nt] = __builtin_amdgcn_mfma_f32_16x16x32_bf16(a[mt], bv[nt], acc[mt][nt], 0, 0, 0);
        }
    }

    float* uo = ks ? u1 : u0;
    #pragma unroll
    for (int mt = 0; mt < 5; ++mt) {
        int grow0 = mt * 16 + slot * 4;
        if (grow0 < 72) {
            int img = grow0 >= 36;
            int hwb = grow0 - 36 * img;
            const int b = b0 + img;
            #pragma unroll
            for (int nt = 0; nt < 4; ++nt) {
                int oc = wc * 64 + nt * 16 + r16;
                float pb = ks ? 0.f : pcb[oc];
                float4v v = acc[mt][nt];
                v.x += pb; v.y += pb; v.z += pb; v.w += pb;
                *(float4v*)(uo + (size_t)b * 9216 + oc * 36 + hwb) = v;
            }
        }
    }
}

// ---------------------------------------------------------------------------
// routing: grid 576 = 144 rc (8 W-rows) x 4 bc (128 images); 256 thr.
// u-tile staging FUSES u0+u1 sum AND squash (per-capsule, in-register):
// no separate squash kernel, u never materialized squashed in global.
// Thread = (oq, img) handles TWO images; W LDS-reads shared by both.
// ---------------------------------------------------------------------------
__global__ __launch_bounds__(256, 2) void k_route3(const float* __restrict__ u0,
                                                   const float* __restrict__ u1,
                                                   const float* __restrict__ W,
                                                   const float* __restrict__ vsum,
                                                   float* __restrict__ spart, int iter)
{
    const int bid = blockIdx.x;
    const int rc = bid % 144;
    const int bc = bid / 144;          // 0..3
    const int r0 = rc * 8;
    const int b0 = bc * 128;
    const int t = threadIdx.x;
    const int oq = t & 3;
    const int img = t >> 2;            // 0..63
    const int bA = b0 + img, bB = bA + 64;

    __shared__ alignas(16) float Wl[10240];     // 40KB: 8 rows x 320 f4, swizzled
    __shared__ alignas(16) float ul[128 * 68];  // 34.8KB: u tile, stride 68

    #pragma unroll
    for (int k = 0; k < 10; ++k) {
        int e = t + k * 256;
        int rr = e / 320, rest = e - rr * 320;
        float4v val = *(const float4v*)(W + (size_t)(r0 + rr) * 1280 + rest * 4);
        int es = e ^ ((e >> 3) & 3);
        *(float4v*)(Wl + es * 4) = val;
    }
    // stage u tile: 1024 capsules (128 img x 8); sum partials + squash inline
    #pragma unroll
    for (int k = 0; k < 4; ++k) {
        int e = t + k * 256;
        int im = e >> 3, cap = e & 7;
        size_t gb = (size_t)(b0 + im) * 9216 + rc * 64 + cap * 8;
        const float4v* pA = (const float4v*)(u0 + gb);
        const float4v* pB = (const float4v*)(u1 + gb);
        float4v a = pA[0] + pB[0];
        float4v c = pA[1] + pB[1];
        float sq = a.x * a.x + a.y * a.y + a.z * a.z + a.w * a.w
                 + c.x * c.x + c.y * c.y + c.z * c.z + c.w * c.w;
        float scale = (sq / (1.f + sq)) / sqrtf(sq + EPSF);
        a *= scale; c *= scale;
        *(float4v*)(ul + im * 68 + cap * 8) = a;
        *(float4v*)(ul + im * 68 + cap * 8 + 4) = c;
    }
    __syncthreads();

    float4v accA[10], accB[10];
    #pragma unroll
    for (int j = 0; j < 10; ++j) {
        accA[j] = (float4v){0.f, 0.f, 0.f, 0.f};
        accB[j] = (float4v){0.f, 0.f, 0.f, 0.f};
    }

    const float* upA = ul + img * 68;
    const float* upB = ul + (img + 64) * 68;

    for (int r = 0; r < 8; ++r) {
        float4v uA0 = *(const float4v*)(upA + r * 8);
        float4v uA1 = *(const float4v*)(upA + r * 8 + 4);
        float4v uB0 = *(const float4v*)(upB + r * 8);
        float4v uB1 = *(const float4v*)(upB + r * 8 + 4);
        float4v uhA[10], uhB[10];
        #pragma unroll
        for (int j = 0; j < 10; ++j) {
            #pragma unroll
            for (int oo = 0; oo < 4; ++oo) {
                int un = r * 320 + j * 32 + oq * 8 + oo * 2;
                int i0 = un ^ oq;      // (un>>3)&3 == oq here
                int i1 = i0 ^ 1;
                float4v wlo = *(const float4v*)(Wl + i0 * 4);
                float4v whi = *(const float4v*)(Wl + i1 * 4);
                uhA[j][oo] = wlo.x * uA0.x + wlo.y * uA0.y + wlo.z * uA0.z + wlo.w * uA0.w
                           + whi.x * uA1.x + whi.y * uA1.y + whi.z * uA1.z + whi.w * uA1.w;
                uhB[j][oo] = wlo.x * uB0.x + wlo.y * uB0.y + wlo.z * uB0.z + wlo.w * uB0.w
                           + whi.x * uB1.x + whi.y * uB1.y + whi.z * uB1.z + whi.w * uB1.w;
            }
        }
        if (iter > 0) {
            #pragma unroll 2
            for (int half = 0; half < 2; ++half) {
                const int b = half ? bB : bA;
                float4v* uh = half ? uhB : uhA;
                float4v* acc = half ? accB : accA;
                float q[10];
                #pragma unroll
                for (int j = 0; j < 10; ++j) {
                    float4v vj = *(const float4v*)(vsum + (size_t)b * 160 + j * 16 + oq * 4);
                    float qp = uh[j].x * vj.x + uh[j].y * vj.y
                             + uh[j].z * vj.z + uh[j].w * vj.w;
                    qp += __shfl_xor(qp, 1);
                    qp += __shfl_xor(qp, 2);
                    q[j] = qp;
                }
                float mx = q[0];
                #pragma unroll
                for (int j = 1; j < 10; ++j) mx = fmaxf(mx, q[j]);
                float ssum = 0.f;
                float c[10];
                #pragma unroll
                for (int j = 0; j < 10; ++j) { c[j] = __expf(q[j] - mx); ssum += c[j]; }
                float inv = 1.f / ssum;
                #pragma unroll
                for (int j = 0; j < 10; ++j) acc[j] += (c[j] * inv) * uh[j];
            }
        } else {
            #pragma unroll
            for (int j = 0; j < 10; ++j) {
                accA[j] += 0.1f * uhA[j];
                accB[j] += 0.1f * uhB[j];
            }
        }
    }

    float* dstA = spart + ((size_t)rc * 512 + bA) * 160 + oq * 4;
    float* dstB = spart + ((size_t)rc * 512 + bB) * 160 + oq * 4;
    #pragma unroll
    for (int j = 0; j < 10; ++j) {
        *(float4v*)(dstA + j * 16) = accA[j];
        *(float4v*)(dstB + j * 16) = accB[j];
    }
}

// ---------------------------------------------------------------------------
// finish: sum 144 partials -> squash -> v; vsum update; iter==2 writes outputs
// ---------------------------------------------------------------------------
__global__ void k_finish(const float* __restrict__ spart, float* __restrict__ vsum,
                         float* __restrict__ obj, float* __restrict__ yprob, int iter)
{
    const int b = blockIdx.x, t = threadIdx.x;
    if (t < 160) {
        const float* sp = spart + (size_t)b * 160 + t;
        float sv = 0.f;
        #pragma unroll 8
        for (int rc = 0; rc < 144; ++rc)
            sv += sp[(size_t)rc * 81920];
        float sq = sv * sv;
        sq += __shfl_xor(sq, 1); sq += __shfl_xor(sq, 2);
        sq += __shfl_xor(sq, 4); sq += __shfl_xor(sq, 8);
        float v = sv * (sq / (1.f + sq)) / sqrtf(sq + EPSF);
        float pv = (iter > 0) ? vsum[b * 160 + t] : 0.f;
        vsum[b * 160 + t] = pv + v;
        if (iter == 2) {
            obj[b * 160 + t] = v;
            float vv = v * v;
            vv += __shfl_xor(vv, 1); vv += __shfl_xor(vv, 2);
            vv += __shfl_xor(vv, 4); vv += __shfl_xor(vv, 8);
            if ((t & 15) == 0) yprob[b * 10 + (t >> 4)] = sqrtf(vv + EPSF);
        }
    }
}

// ---------------------------------------------------------------------------
// mlp1 with label-gather: h1[m][n] = relu(b1[n] + sum_{o<16} v[m][lab*16+o] *
// w1[n][lab*16+o]) — exploits one-hot mask (K=16 not 160). grid 64 (8 m each).
// ---------------------------------------------------------------------------
__global__ __launch_bounds__(256) void k_mlp1g(const float* __restrict__ obj,
                                               const int* __restrict__ label,
                                               const float* __restrict__ w1,
                                               const float* __restrict__ b1,
                                               float* __restrict__ h1)
{
    const int b0 = blockIdx.x * 8;
    const int t = threadIdx.x;
    __shared__ float vl[8][16];
    __shared__ int labs[8];
    if (t < 8) labs[t] = label[b0 + t];
    __syncthreads();
    if (t < 128) {
        int m = t >> 4, o = t & 15;
        vl[m][o] = obj[(size_t)(b0 + m) * 160 + labs[m] * 16 + o];
    }
    __syncthreads();
    #pragma unroll 2
    for (int nn = 0; nn < 2; ++nn) {
        const int n = t + nn * 256;
        const float bs = b1[n];
        #pragma unroll
        for (int m = 0; m < 8; ++m) {
            const float4v* wp = (const float4v*)(w1 + (size_t)n * 160 + labs[m] * 16);
            float4v w0 = wp[0], w1v = wp[1], w2 = wp[2], w3 = wp[3];
            float q = bs;
            q += vl[m][0]  * w0.x  + vl[m][1]  * w0.y  + vl[m][2]  * w0.z  + vl[m][3]  * w0.w;
            q += vl[m][4]  * w1v.x + vl[m][5]  * w1v.y + vl[m][6]  * w1v.z + vl[m][7]  * w1v.w;
            q += vl[m][8]  * w2.x  + vl[m][9]  * w2.y  + vl[m][10] * w2.z  + vl[m][11] * w2.w;
            q += vl[m][12] * w3.x  + vl[m][13] * w3.y  + vl[m][14] * w3.z  + vl[m][15] * w3.w;
            h1[(size_t)(b0 + m) * 512 + n] = fmaxf(q, 0.f);
        }
    }
}

// ---------------------------------------------------------------------------
// decoder GEMM: C[m,n] = act(bias[n] + sum_k A[m,k]*Wt[n,k]); M=512.
// ---------------------------------------------------------------------------
__global__ void k_mlp(const float* __restrict__ A, const float* __restrict__ Wt,
                      const float* __restrict__ bias, float* __restrict__ C,
                      int N, int K, int act)
{
    const int m0 = blockIdx.x * 32;
    const int n0 = blockIdx.y * 32;
    const int t  = threadIdx.x;
    const int tn = t & 31, tg = t >> 5;
    __shared__ float As[32][33];
    __shared__ float Ws[32][33];
    float acc[4] = {0.f, 0.f, 0.f, 0.f};
    for (int k0 = 0; k0 < K; k0 += 32) {
        __syncthreads();
        for (int idx = t; idx < 1024; idx += 256) {
            int rr = idx >> 5, kk = idx & 31;
            As[rr][kk] = A[(size_t)(m0 + rr) * K + k0 + kk];
            int n = n0 + rr;
            Ws[rr][kk] = (n < N) ? Wt[(size_t)n * K + k0 + kk] : 0.f;
        }
        __syncthreads();
        #pragma unroll 8
        for (int kk = 0; kk < 32; ++kk) {
            float bv = Ws[tn][kk];
            #pragma unroll
            for (int i = 0; i < 4; ++i)
                acc[i] += As[tg * 4 + i][kk] * bv;
        }
    }
    int n = n0 + tn;
    if (n < N) {
        float bs = bias[n];
        #pragma unroll
        for (int i = 0; i < 4; ++i) {
            float vv = acc[i] + bs;
            vv = (act == 0) ? fmaxf(vv, 0.f) : 1.f / (1.f + expf(-vv));
            C[(size_t)(m0 + tg * 4 + i) * N + n] = vv;
        }
    }
}

// ---------------------------------------------------------------------------
extern "C" void kernel_launch(void* const* d_in, const int* in_sizes, int n_in,
                              void* d_out, int out_size, void* d_ws, size_t ws_size,
                              hipStream_t stream)
{
    const float* image  = (const float*)d_in[0];
    const int*   label  = (const int*)  d_in[1];
    const float* conv_w = (const float*)d_in[2];
    const float* conv_b = (const float*)d_in[3];
    const float* pc_w   = (const float*)d_in[4];
    const float* pc_b   = (const float*)d_in[5];
    const float* Wrt    = (const float*)d_in[6];
    const float* dw1 = (const float*)d_in[7];
    const float* db1 = (const float*)d_in[8];
    const float* dw2 = (const float*)d_in[9];
    const float* db2 = (const float*)d_in[10];
    const float* dw3 = (const float*)d_in[11];
    const float* db3 = (const float*)d_in[12];
    float* out = (float*)d_out;

    char* p = (char*)d_ws;
    __hip_bfloat16* xt  = (__hip_bfloat16*)p; p += 104857600;
    float* u      = (float*)p; p += 18874368;   // u0 (ks0 partial + bias)
    float* u1     = (float*)p; p += 18874368;   // ks1 partial
    __hip_bfloat16* Bw2 = (__hip_bfloat16*)p; p += 10616832;
    float* vsum   = (float*)p; p += 327680;
    float* h1     = (float*)p; p += 1048576;
    float* h2     = (float*)p; p += 2097152;

    // spart [144][512][160] f32 (47.2 MB) aliases xt (dead after k_conv2,
    // fully rewritten by conv1 each launch -> deterministic across replays).
    float* spart = (float*)xt;

    float* obj   = out;            // [512,10,16,1]
    float* recon = out + 81920;    // [512,1,28,28]
    float* yprob = out + 483328;   // [512,10]

    k_bw2<<<256, 256, 0, stream>>>(pc_w, Bw2);
    k_conv1<<<512, 256, 0, stream>>>(image, conv_w, conv_b, xt);
    k_conv2<<<512, 256, 0, stream>>>(xt, Bw2, pc_b, u, u1);
    for (int it = 0; it < 3; ++it) {
        k_route3<<<576, 256, 0, stream>>>(u, u1, Wrt, vsum, spart, it);
        k_finish<<<512, 192, 0, stream>>>(spart, vsum, obj, yprob, it);
    }
    k_mlp1g<<<64, 256, 0, stream>>>(obj, label, dw1, db1, h1);
    k_mlp<<<dim3(16, 32), 256, 0, stream>>>(h1, dw2, db2, h2, 1024, 512, 0);
    k_mlp<<<dim3(16, 25), 256, 0, stream>>>(h2, dw3, db3, recon, 784, 1024, 1);
}

// Round 20
// 680.996 us; speedup vs baseline: 1.2808x; 1.0182x over previous
//
#include <hip/hip_runtime.h>
#include <hip/hip_bf16.h>

#define EPSF 1e-8f

typedef __attribute__((ext_vector_type(8))) short short8v;
typedef __attribute__((ext_vector_type(4))) float float4v;

static __device__ __forceinline__ unsigned short f2bf_bits(float x)
{
    return __builtin_bit_cast(unsigned short, __float2bfloat16(x));
}

// ---------------------------------------------------------------------------
// k_prep: fused bw2 (blocks 0-255) + conv1 (blocks 256-767).
// bw2: pc_w f32 [256oc][256ic][81k] -> Bw2 coalesced per-wave chunks.
// conv1: image -> x_t bf16 [b][icc][pos=400][64B unit, slot-XOR-permuted],
//        rolling 9-row register window.
// ---------------------------------------------------------------------------
__global__ __launch_bounds__(256) void k_prep(const float* __restrict__ pw,
                                              __hip_bfloat16* __restrict__ Bw2,
                                              const float* __restrict__ img,
                                              const float* __restrict__ cw,
                                              const float* __restrict__ cb,
                                              __hip_bfloat16* __restrict__ xt)
{
    __shared__ alignas(16) char shmem[41472];
    const int bid = blockIdx.x;
    const int t = threadIdx.x;

    if (bid < 256) {
        // ---- bw2 ----
        const int oc = bid;
        unsigned short* wl = (unsigned short*)shmem;   // [ic][k] bf16 bits
        for (int i = t; i < 20736; i += 256)
            wl[i] = f2bf_bits(pw[(size_t)oc * 20736 + i]);
        __syncthreads();
        const int r16 = oc & 15, nt = (oc >> 4) & 3, wcq = oc >> 6;
        for (int e = t; e < 2592; e += 256) {
            const int kidx = e >> 5, icc = (e >> 2) & 7, slot = e & 3;
            short8v v;
            #pragma unroll
            for (int i = 0; i < 8; ++i)
                v[i] = (short)wl[(icc * 32 + slot * 8 + i) * 81 + kidx];
            const int chunk = ((kidx * 8 + icc) * 4 + wcq) * 4 + nt;
            *(short8v*)(Bw2 + (size_t)chunk * 512 + (slot * 16 + r16) * 8) = v;
        }
        return;
    }

    // ---- conv1 ----
    const int b = bid - 256;
    const int c = t;
    float* simg = (float*)shmem;
    for (int i = c; i < 784; i += 256) simg[i] = img[b * 784 + i];
    float wreg[81];
    const float* wp = cw + c * 81;
    #pragma unroll
    for (int k = 0; k < 81; ++k) wreg[k] = wp[k];
    const float bias = cb[c];
    __syncthreads();

    const int icc = c >> 5, slot = (c >> 3) & 3, ic8 = c & 7;
    char* xbase = (char*)xt + ((size_t)b * 8 + icc) * 25600;

    for (int wg = 0; wg < 5; ++wg) {
        const float* base = &simg[wg * 4];
        float win[9][12];
        #pragma unroll
        for (int r = 0; r < 8; ++r) {
            const float4v* rp = (const float4v*)(base + r * 28);
            float4v A = rp[0], B = rp[1], C = rp[2];
            win[r][0] = A.x; win[r][1] = A.y; win[r][2]  = A.z; win[r][3]  = A.w;
            win[r][4] = B.x; win[r][5] = B.y; win[r][6]  = B.z; win[r][7]  = B.w;
            win[r][8] = C.x; win[r][9] = C.y; win[r][10] = C.z; win[r][11] = C.w;
        }
        #pragma unroll
        for (int h = 0; h < 20; ++h) {
            {
                const int ws = (h + 8) % 9;
                const float4v* rp = (const float4v*)(base + (h + 8) * 28);
                float4v A = rp[0], B = rp[1], C = rp[2];
                win[ws][0] = A.x; win[ws][1] = A.y; win[ws][2]  = A.z; win[ws][3]  = A.w;
                win[ws][4] = B.x; win[ws][5] = B.y; win[ws][6]  = B.z; win[ws][7]  = B.w;
                win[ws][8] = C.x; win[ws][9] = C.y; win[ws][10] = C.z; win[ws][11] = C.w;
            }
            float acc[4] = {bias, bias, bias, bias};
            #pragma unroll
            for (int ky = 0; ky < 9; ++ky) {
                const int rs = (h + ky) % 9;
                #pragma unroll
                for (int kx = 0; kx < 9; ++kx) {
                    const float wv = wreg[ky * 9 + kx];
                    #pragma unroll
                    for (int i = 0; i < 4; ++i)
                        acc[i] = fmaf(win[rs][kx + i], wv, acc[i]);
                }
            }
            #pragma unroll
            for (int i = 0; i < 4; ++i) {
                int w = wg * 4 + i;
                float av = fmaxf(acc[i], 0.f);
                int pos = h * 20 + (w & 1) * 10 + (w >> 1);
                int off = pos * 64 + ((slot ^ ((pos >> 1) & 3)) << 4) + ic8 * 2;
                *(unsigned short*)(xbase + off) = f2bf_bits(av);
            }
        }
    }
}

// ---------------------------------------------------------------------------
// async stage of one icc-chunk (2 images, 51200 B) into LDS; 256 threads.
// ---------------------------------------------------------------------------
__device__ __forceinline__ void stage_x(const __hip_bfloat16* __restrict__ xt,
                                        char* dst, int b0, int icc, int t)
{
    const __hip_bfloat16* base0 = xt + ((size_t)(b0    ) * 8 + icc) * 12800;
    const __hip_bfloat16* base1 = xt + ((size_t)(b0 + 1) * 8 + icc) * 12800;
    #pragma unroll
    for (int k = 0; k < 12; ++k) {
        const int unit = t + k * 256;
        const __hip_bfloat16* gp = (unit < 1600) ? (base0 + unit * 8)
                                                 : (base1 + (unit - 1600) * 8);
        __builtin_amdgcn_global_load_lds(
            (const __attribute__((address_space(1))) unsigned int*)gp,
            (__attribute__((address_space(3))) unsigned int*)(dst + unit * 16),
            16, 0, 0);
    }
    if (t < 128) {
        const int unit = 3072 + t;
        const __hip_bfloat16* gp = base1 + (unit - 1600) * 8;
        __builtin_amdgcn_global_load_lds(
            (const __attribute__((address_space(1))) unsigned int*)gp,
            (__attribute__((address_space(3))) unsigned int*)(dst + unit * 16),
            16, 0, 0);
    }
}

// ---------------------------------------------------------------------------
// conv2 via MFMA, packed-M + K-split: grid 512 = 256 pairs x 2 ks (4 icc each).
// 256 thr = 4 waves (wc). Rows of BOTH images packed into 5 shared 16-row
// tiles -> 20 MFMA per 4KB B-load. Partials -> u0 (ks0,+bias) / u1.
// ---------------------------------------------------------------------------
__global__ __launch_bounds__(256, 2) void k_conv2(const __hip_bfloat16* __restrict__ xt,
                                                  const __hip_bfloat16* __restrict__ Bw2,
                                                  const float* __restrict__ pcb,
                                                  float* __restrict__ u0,
                                                  float* __restrict__ u1)
{
    const int pair = blockIdx.x >> 1;
    const int ks = blockIdx.x & 1;
    const int b0 = pair * 2;
    const int t = threadIdx.x;
    const int lane = t & 63, wc = t >> 6;
    const int r16 = lane & 15, slot = lane >> 4;

    __shared__ alignas(16) char xs[51200];

    int aimg[5], lc[5];
    #pragma unroll
    for (int mt = 0; mt < 5; ++mt) {
        int grow = mt * 16 + r16;
        int img = (grow >= 36 && grow < 72) ? 1 : 0;
        int hw = (grow < 72) ? (grow - 36 * img) : 0;
        int h = hw / 6, w = hw - h * 6;
        aimg[mt] = img * 25600;
        lc[mt] = 40 * h + w;
    }

    float4v acc[5][4];
    #pragma unroll
    for (int mt = 0; mt < 5; ++mt)
        #pragma unroll
        for (int nt = 0; nt < 4; ++nt)
            acc[mt][nt] = (float4v){0.f, 0.f, 0.f, 0.f};

    for (int i4 = 0; i4 < 4; ++i4) {
        const int icc = ks * 4 + i4;
        __syncthreads();
        stage_x(xt, xs, b0, icc, t);
        __syncthreads();

        const __hip_bfloat16* bp = Bw2 + ((size_t)icc * 4 + wc) * 2048 + lane * 8;

        #pragma unroll 3
        for (int kidx = 0; kidx < 81; ++kidx) {
            int ky = kidx / 9, kx = kidx - ky * 9;
            int scalK = 20 * ky + 10 * (kx & 1) + (kx >> 1);
            short8v a[5];
            #pragma unroll
            for (int mt = 0; mt < 5; ++mt) {
                int pos = lc[mt] + scalK;
                int off = aimg[mt] + pos * 64 + (((slot ^ (pos >> 1)) & 3) << 4);
                a[mt] = *(const short8v*)(xs + off);
            }
            const __hip_bfloat16* bq = bp + (size_t)kidx * 65536;
            short8v bv[4];
            #pragma unroll
            for (int nt = 0; nt < 4; ++nt)
                bv[nt] = *(const short8v*)(bq + nt * 512);
            #pragma unroll
            for (int mt = 0; mt < 5; ++mt)
                #pragma unroll
                for (int nt = 0; nt < 4; ++nt)
                    acc[mt][nt] = __builtin_amdgcn_mfma_f32_16x16x32_bf16(a[mt], bv[nt], acc[mt][nt], 0, 0, 0);
        }
    }

    float* uo = ks ? u1 : u0;
    #pragma unroll
    for (int mt = 0; mt < 5; ++mt) {
        int grow0 = mt * 16 + slot * 4;
        if (grow0 < 72) {
            int img = grow0 >= 36;
            int hwb = grow0 - 36 * img;
            const int b = b0 + img;
            #pragma unroll
            for (int nt = 0; nt < 4; ++nt) {
                int oc = wc * 64 + nt * 16 + r16;
                float pb = ks ? 0.f : pcb[oc];
                float4v v = acc[mt][nt];
                v.x += pb; v.y += pb; v.z += pb; v.w += pb;
                *(float4v*)(uo + (size_t)b * 9216 + oc * 36 + hwb) = v;
            }
        }
    }
}

// ---------------------------------------------------------------------------
// routing: grid 576 = 144 rc (8 W-rows) x 4 bc (128 images); 256 thr.
// u-tile staging fuses u0+u1 sum AND squash in-register.
// Thread = (oq, img) handles TWO images; W LDS-reads shared by both.
// ---------------------------------------------------------------------------
__global__ __launch_bounds__(256, 2) void k_route3(const float* __restrict__ u0,
                                                   const float* __restrict__ u1,
                                                   const float* __restrict__ W,
                                                   const float* __restrict__ vsum,
                                                   float* __restrict__ spart, int iter)
{
    const int bid = blockIdx.x;
    const int rc = bid % 144;
    const int bc = bid / 144;          // 0..3
    const int r0 = rc * 8;
    const int b0 = bc * 128;
    const int t = threadIdx.x;
    const int oq = t & 3;
    const int img = t >> 2;            // 0..63
    const int bA = b0 + img, bB = bA + 64;

    __shared__ alignas(16) float Wl[10240];     // 40KB: 8 rows x 320 f4, swizzled
    __shared__ alignas(16) float ul[128 * 68];  // 34.8KB: u tile, stride 68

    #pragma unroll
    for (int k = 0; k < 10; ++k) {
        int e = t + k * 256;
        int rr = e / 320, rest = e - rr * 320;
        float4v val = *(const float4v*)(W + (size_t)(r0 + rr) * 1280 + rest * 4);
        int es = e ^ ((e >> 3) & 3);
        *(float4v*)(Wl + es * 4) = val;
    }
    #pragma unroll
    for (int k = 0; k < 4; ++k) {
        int e = t + k * 256;
        int im = e >> 3, cap = e & 7;
        size_t gb = (size_t)(b0 + im) * 9216 + rc * 64 + cap * 8;
        const float4v* pA = (const float4v*)(u0 + gb);
        const float4v* pB = (const float4v*)(u1 + gb);
        float4v a = pA[0] + pB[0];
        float4v c = pA[1] + pB[1];
        float sq = a.x * a.x + a.y * a.y + a.z * a.z + a.w * a.w
                 + c.x * c.x + c.y * c.y + c.z * c.z + c.w * c.w;
        float scale = (sq / (1.f + sq)) / sqrtf(sq + EPSF);
        a *= scale; c *= scale;
        *(float4v*)(ul + im * 68 + cap * 8) = a;
        *(float4v*)(ul + im * 68 + cap * 8 + 4) = c;
    }
    __syncthreads();

    float4v accA[10], accB[10];
    #pragma unroll
    for (int j = 0; j < 10; ++j) {
        accA[j] = (float4v){0.f, 0.f, 0.f, 0.f};
        accB[j] = (float4v){0.f, 0.f, 0.f, 0.f};
    }

    const float* upA = ul + img * 68;
    const float* upB = ul + (img + 64) * 68;

    for (int r = 0; r < 8; ++r) {
        float4v uA0 = *(const float4v*)(upA + r * 8);
        float4v uA1 = *(const float4v*)(upA + r * 8 + 4);
        float4v uB0 = *(const float4v*)(upB + r * 8);
        float4v uB1 = *(const float4v*)(upB + r * 8 + 4);
        float4v uhA[10], uhB[10];
        #pragma unroll
        for (int j = 0; j < 10; ++j) {
            #pragma unroll
            for (int oo = 0; oo < 4; ++oo) {
                int un = r * 320 + j * 32 + oq * 8 + oo * 2;
                int i0 = un ^ oq;
                int i1 = i0 ^ 1;
                float4v wlo = *(const float4v*)(Wl + i0 * 4);
                float4v whi = *(const float4v*)(Wl + i1 * 4);
                uhA[j][oo] = wlo.x * uA0.x + wlo.y * uA0.y + wlo.z * uA0.z + wlo.w * uA0.w
                           + whi.x * uA1.x + whi.y * uA1.y + whi.z * uA1.z + whi.w * uA1.w;
                uhB[j][oo] = wlo.x * uB0.x + wlo.y * uB0.y + wlo.z * uB0.z + wlo.w * uB0.w
                           + whi.x * uB1.x + whi.y * uB1.y + whi.z * uB1.z + whi.w * uB1.w;
            }
        }
        if (iter > 0) {
            #pragma unroll 2
            for (int half = 0; half < 2; ++half) {
                const int b = half ? bB : bA;
                float4v* uh = half ? uhB : uhA;
                float4v* acc = half ? accB : accA;
                float q[10];
                #pragma unroll
                for (int j = 0; j < 10; ++j) {
                    float4v vj = *(const float4v*)(vsum + (size_t)b * 160 + j * 16 + oq * 4);
                    float qp = uh[j].x * vj.x + uh[j].y * vj.y
                             + uh[j].z * vj.z + uh[j].w * vj.w;
                    qp += __shfl_xor(qp, 1);
                    qp += __shfl_xor(qp, 2);
                    q[j] = qp;
                }
                float mx = q[0];
                #pragma unroll
                for (int j = 1; j < 10; ++j) mx = fmaxf(mx, q[j]);
                float ssum = 0.f;
                float c[10];
                #pragma unroll
                for (int j = 0; j < 10; ++j) { c[j] = __expf(q[j] - mx); ssum += c[j]; }
                float inv = 1.f / ssum;
                #pragma unroll
                for (int j = 0; j < 10; ++j) acc[j] += (c[j] * inv) * uh[j];
            }
        } else {
            #pragma unroll
            for (int j = 0; j < 10; ++j) {
                accA[j] += 0.1f * uhA[j];
                accB[j] += 0.1f * uhB[j];
            }
        }
    }

    float* dstA = spart + ((size_t)rc * 512 + bA) * 160 + oq * 4;
    float* dstB = spart + ((size_t)rc * 512 + bB) * 160 + oq * 4;
    #pragma unroll
    for (int j = 0; j < 10; ++j) {
        *(float4v*)(dstA + j * 16) = accA[j];
        *(float4v*)(dstB + j * 16) = accB[j];
    }
}

// ---------------------------------------------------------------------------
// finish: sum 144 partials -> squash -> v; vsum update; iter==2 writes outputs
// ---------------------------------------------------------------------------
__global__ void k_finish(const float* __restrict__ spart, float* __restrict__ vsum,
                         float* __restrict__ obj, float* __restrict__ yprob, int iter)
{
    const int b = blockIdx.x, t = threadIdx.x;
    if (t < 160) {
        const float* sp = spart + (size_t)b * 160 + t;
        float sv = 0.f;
        #pragma unroll 8
        for (int rc = 0; rc < 144; ++rc)
            sv += sp[(size_t)rc * 81920];
        float sq = sv * sv;
        sq += __shfl_xor(sq, 1); sq += __shfl_xor(sq, 2);
        sq += __shfl_xor(sq, 4); sq += __shfl_xor(sq, 8);
        float v = sv * (sq / (1.f + sq)) / sqrtf(sq + EPSF);
        float pv = (iter > 0) ? vsum[b * 160 + t] : 0.f;
        vsum[b * 160 + t] = pv + v;
        if (iter == 2) {
            obj[b * 160 + t] = v;
            float vv = v * v;
            vv += __shfl_xor(vv, 1); vv += __shfl_xor(vv, 2);
            vv += __shfl_xor(vv, 4); vv += __shfl_xor(vv, 8);
            if ((t & 15) == 0) yprob[b * 10 + (t >> 4)] = sqrtf(vv + EPSF);
        }
    }
}

// ---------------------------------------------------------------------------
// mlp1 with label-gather: h1[m][n] = relu(b1[n] + sum_{o<16} v[m][lab*16+o] *
// w1[n][lab*16+o]) — exploits one-hot mask (K=16 not 160). grid 64 (8 m each).
// f32 throughout (bf16 decoder failed the 2e-2 threshold in R19).
// ---------------------------------------------------------------------------
__global__ __launch_bounds__(256) void k_mlp1g(const float* __restrict__ obj,
                                               const int* __restrict__ label,
                                               const float* __restrict__ w1,
                                               const float* __restrict__ b1,
                                               float* __restrict__ h1)
{
    const int b0 = blockIdx.x * 8;
    const int t = threadIdx.x;
    __shared__ float vl[8][16];
    __shared__ int labs[8];
    if (t < 8) labs[t] = label[b0 + t];
    __syncthreads();
    if (t < 128) {
        int m = t >> 4, o = t & 15;
        vl[m][o] = obj[(size_t)(b0 + m) * 160 + labs[m] * 16 + o];
    }
    __syncthreads();
    #pragma unroll 2
    for (int nn = 0; nn < 2; ++nn) {
        const int n = t + nn * 256;
        const float bs = b1[n];
        #pragma unroll
        for (int m = 0; m < 8; ++m) {
            const float4v* wp = (const float4v*)(w1 + (size_t)n * 160 + labs[m] * 16);
            float4v w0 = wp[0], w1v = wp[1], w2 = wp[2], w3 = wp[3];
            float q = bs;
            q += vl[m][0]  * w0.x  + vl[m][1]  * w0.y  + vl[m][2]  * w0.z  + vl[m][3]  * w0.w;
            q += vl[m][4]  * w1v.x + vl[m][5]  * w1v.y + vl[m][6]  * w1v.z + vl[m][7]  * w1v.w;
            q += vl[m][8]  * w2.x  + vl[m][9]  * w2.y  + vl[m][10] * w2.z  + vl[m][11] * w2.w;
            q += vl[m][12] * w3.x  + vl[m][13] * w3.y  + vl[m][14] * w3.z  + vl[m][15] * w3.w;
            h1[(size_t)(b0 + m) * 512 + n] = fmaxf(q, 0.f);
        }
    }
}

// ---------------------------------------------------------------------------
// decoder GEMM (f32): C[m,n] = act(bias[n] + sum_k A[m,k]*Wt[n,k]); M=512.
// ---------------------------------------------------------------------------
__global__ void k_mlp(const float* __restrict__ A, const float* __restrict__ Wt,
                      const float* __restrict__ bias, float* __restrict__ C,
                      int N, int K, int act)
{
    const int m0 = blockIdx.x * 32;
    const int n0 = blockIdx.y * 32;
    const int t  = threadIdx.x;
    const int tn = t & 31, tg = t >> 5;
    __shared__ float As[32][33];
    __shared__ float Ws[32][33];
    float acc[4] = {0.f, 0.f, 0.f, 0.f};
    for (int k0 = 0; k0 < K; k0 += 32) {
        __syncthreads();
        for (int idx = t; idx < 1024; idx += 256) {
            int rr = idx >> 5, kk = idx & 31;
            As[rr][kk] = A[(size_t)(m0 + rr) * K + k0 + kk];
            int n = n0 + rr;
            Ws[rr][kk] = (n < N) ? Wt[(size_t)n * K + k0 + kk] : 0.f;
        }
        __syncthreads();
        #pragma unroll 8
        for (int kk = 0; kk < 32; ++kk) {
            float bv = Ws[tn][kk];
            #pragma unroll
            for (int i = 0; i < 4; ++i)
                acc[i] += As[tg * 4 + i][kk] * bv;
        }
    }
    int n = n0 + tn;
    if (n < N) {
        float bs = bias[n];
        #pragma unroll
        for (int i = 0; i < 4; ++i) {
            float vv = acc[i] + bs;
            vv = (act == 0) ? fmaxf(vv, 0.f) : 1.f / (1.f + expf(-vv));
            C[(size_t)(m0 + tg * 4 + i) * N + n] = vv;
        }
    }
}

// ---------------------------------------------------------------------------
extern "C" void kernel_launch(void* const* d_in, const int* in_sizes, int n_in,
                              void* d_out, int out_size, void* d_ws, size_t ws_size,
                              hipStream_t stream)
{
    const float* image  = (const float*)d_in[0];
    const int*   label  = (const int*)  d_in[1];
    const float* conv_w = (const float*)d_in[2];
    const float* conv_b = (const float*)d_in[3];
    const float* pc_w   = (const float*)d_in[4];
    const float* pc_b   = (const float*)d_in[5];
    const float* Wrt    = (const float*)d_in[6];
    const float* dw1 = (const float*)d_in[7];
    const float* db1 = (const float*)d_in[8];
    const float* dw2 = (const float*)d_in[9];
    const float* db2 = (const float*)d_in[10];
    const float* dw3 = (const float*)d_in[11];
    const float* db3 = (const float*)d_in[12];
    float* out = (float*)d_out;

    char* p = (char*)d_ws;
    __hip_bfloat16* xt  = (__hip_bfloat16*)p; p += 104857600;
    float* u      = (float*)p; p += 18874368;   // u0 (ks0 partial + bias)
    float* u1     = (float*)p; p += 18874368;   // ks1 partial
    __hip_bfloat16* Bw2 = (__hip_bfloat16*)p; p += 10616832;
    float* vsum   = (float*)p; p += 327680;
    float* h1     = (float*)p; p += 1048576;
    float* h2     = (float*)p; p += 2097152;

    // spart [144][512][160] f32 (47.2 MB) aliases xt (dead after k_conv2,
    // fully rewritten by k_prep each launch -> deterministic across replays).
    float* spart = (float*)xt;

    float* obj   = out;            // [512,10,16,1]
    float* recon = out + 81920;    // [512,1,28,28]
    float* yprob = out + 483328;   // [512,10]

    k_prep<<<768, 256, 0, stream>>>(pc_w, Bw2, image, conv_w, conv_b, xt);
    k_conv2<<<512, 256, 0, stream>>>(xt, Bw2, pc_b, u, u1);
    for (int it = 0; it < 3; ++it) {
        k_route3<<<576, 256, 0, stream>>>(u, u1, Wrt, vsum, spart, it);
        k_finish<<<512, 192, 0, stream>>>(spart, vsum, obj, yprob, it);
    }
    k_mlp1g<<<64, 256, 0, stream>>>(obj, label, dw1, db1, h1);
    k_mlp<<<dim3(16, 32), 256, 0, stream>>>(h1, dw2, db2, h2, 1024, 512, 0);
    k_mlp<<<dim3(16, 25), 256, 0, stream>>>(h2, dw3, db3, recon, 784, 1024, 1);
}

// Round 21
// 639.317 us; speedup vs baseline: 1.3643x; 1.0652x over previous
//
#include <hip/hip_runtime.h>
#include <hip/hip_bf16.h>

#define EPSF 1e-8f

typedef __attribute__((ext_vector_type(8))) short short8v;
typedef __attribute__((ext_vector_type(4))) float float4v;

static __device__ __forceinline__ unsigned short f2bf_bits(float x)
{
    return __builtin_bit_cast(unsigned short, __float2bfloat16(x));
}

// ---------------------------------------------------------------------------
// k_prep: fused bw2 (blocks 0-255) + conv1-MFMA (blocks 256-767).
// bw2: pc_w f32 -> Bw2 coalesced per-wave chunks (unchanged).
// conv1: im2col MFMA GEMM per image: M=400 pos (25x16), N=256 ch, K=81->96.
//   A from bf16 image in LDS (offset table, zero-pad for k>=81);
//   B from per-block LDS Bw1c[12][256][8] bf16 (chunk stride 2056 = pad 16B).
//   Fragment layouts identical to the verified conv2 mappings.
// ---------------------------------------------------------------------------
__global__ __launch_bounds__(256) void k_prep(const float* __restrict__ pw,
                                              __hip_bfloat16* __restrict__ Bw2,
                                              const float* __restrict__ img,
                                              const float* __restrict__ cw,
                                              const float* __restrict__ cb,
                                              __hip_bfloat16* __restrict__ xt)
{
    __shared__ alignas(16) char shmem[54016];
    const int bid = blockIdx.x;
    const int t = threadIdx.x;

    if (bid < 256) {
        // ---- bw2 ----
        const int oc = bid;
        unsigned short* wl = (unsigned short*)shmem;   // [ic][k] bf16 bits
        for (int i = t; i < 20736; i += 256)
            wl[i] = f2bf_bits(pw[(size_t)oc * 20736 + i]);
        __syncthreads();
        const int r16 = oc & 15, nt = (oc >> 4) & 3, wcq = oc >> 6;
        for (int e = t; e < 2592; e += 256) {
            const int kidx = e >> 5, icc = (e >> 2) & 7, slot = e & 3;
            short8v v;
            #pragma unroll
            for (int i = 0; i < 8; ++i)
                v[i] = (short)wl[(icc * 32 + slot * 8 + i) * 81 + kidx];
            const int chunk = ((kidx * 8 + icc) * 4 + wcq) * 4 + nt;
            *(short8v*)(Bw2 + (size_t)chunk * 512 + (slot * 16 + r16) * 8) = v;
        }
        return;
    }

    // ---- conv1 via MFMA ----
    const int b = bid - 256;
    const int lane = t & 63, wid = t >> 6;
    const int r16 = lane & 15, slot = lane >> 4;

    unsigned short* simgbf = (unsigned short*)shmem;            // [1600] bf16
    int* offT             = (int*)(shmem + 3200);               // [96]
    unsigned short* Bw1c  = (unsigned short*)(shmem + 3584);    // [12*2056]
    float* cbl            = (float*)(shmem + 52928);            // [256]

    for (int i = t; i < 784; i += 256) simgbf[i] = f2bf_bits(img[b * 784 + i]);
    for (int i = 784 + t; i < 1600; i += 256) simgbf[i] = 0;
    if (t < 96) offT[t] = (t < 81) ? (t / 9) * 28 + (t % 9) : 1000;
    cbl[t] = cb[t];
    for (int e = t; e < 3072; e += 256) {
        const int chunk = e >> 8, c = e & 255;
        #pragma unroll
        for (int i = 0; i < 8; ++i) {
            const int k = chunk * 8 + i;
            Bw1c[chunk * 2056 + c * 8 + i] =
                (k < 81) ? f2bf_bits(cw[c * 81 + k]) : (unsigned short)0;
        }
    }
    __syncthreads();

    char* xb = (char*)xt + (size_t)b * 8 * 25600;

    for (int m = wid; m < 25; m += 4) {
        const int pos_r = m * 16 + r16;
        const int hh = (pos_r * 3277) >> 16;          // pos_r / 20
        const int ww = pos_r - hh * 20;
        const int abase = hh * 28 + ww;
        short8v a[3];
        #pragma unroll
        for (int ks = 0; ks < 3; ++ks) {
            #pragma unroll
            for (int i = 0; i < 8; ++i) {
                const int k = ks * 32 + slot * 8 + i;
                a[ks][i] = (short)simgbf[abase + offT[k]];
            }
        }
        #pragma unroll 4
        for (int nt = 0; nt < 16; ++nt) {
            float4v acc4 = (float4v){0.f, 0.f, 0.f, 0.f};
            #pragma unroll
            for (int ks = 0; ks < 3; ++ks) {
                short8v bv = *(const short8v*)(Bw1c + (ks * 4 + slot) * 2056
                                               + (nt * 16 + r16) * 8);
                acc4 = __builtin_amdgcn_mfma_f32_16x16x32_bf16(a[ks], bv, acc4, 0, 0, 0);
            }
            const int c = nt * 16 + r16;
            const int icc_ = c >> 5, sl = (c >> 3) & 3, i8 = c & 7;
            const float cbv = cbl[c];
            char* xc = xb + icc_ * 25600 + i8 * 2;
            #pragma unroll
            for (int i = 0; i < 4; ++i) {
                const int pos = m * 16 + slot * 4 + i;
                const int h2 = (pos * 3277) >> 16;
                const int w2 = pos - h2 * 20;
                const int pp = h2 * 20 + (w2 & 1) * 10 + (w2 >> 1);
                const float v = fmaxf(acc4[i] + cbv, 0.f);
                *(unsigned short*)(xc + pp * 64 + ((sl ^ ((pp >> 1) & 3)) << 4)) = f2bf_bits(v);
            }
        }
    }
}

// ---------------------------------------------------------------------------
// async stage of one icc-chunk (2 images, 51200 B) into LDS; 256 threads.
// ---------------------------------------------------------------------------
__device__ __forceinline__ void stage_x(const __hip_bfloat16* __restrict__ xt,
                                        char* dst, int b0, int icc, int t)
{
    const __hip_bfloat16* base0 = xt + ((size_t)(b0    ) * 8 + icc) * 12800;
    const __hip_bfloat16* base1 = xt + ((size_t)(b0 + 1) * 8 + icc) * 12800;
    #pragma unroll
    for (int k = 0; k < 12; ++k) {
        const int unit = t + k * 256;
        const __hip_bfloat16* gp = (unit < 1600) ? (base0 + unit * 8)
                                                 : (base1 + (unit - 1600) * 8);
        __builtin_amdgcn_global_load_lds(
            (const __attribute__((address_space(1))) unsigned int*)gp,
            (__attribute__((address_space(3))) unsigned int*)(dst + unit * 16),
            16, 0, 0);
    }
    if (t < 128) {
        const int unit = 3072 + t;
        const __hip_bfloat16* gp = base1 + (unit - 1600) * 8;
        __builtin_amdgcn_global_load_lds(
            (const __attribute__((address_space(1))) unsigned int*)gp,
            (__attribute__((address_space(3))) unsigned int*)(dst + unit * 16),
            16, 0, 0);
    }
}

// ---------------------------------------------------------------------------
// conv2 via MFMA, packed-M + K-split: grid 512 = 256 pairs x 2 ks (4 icc each).
// 256 thr = 4 waves (wc). Rows of BOTH images packed into 5 shared 16-row
// tiles -> 20 MFMA per 4KB B-load. Partials -> u0 (ks0,+bias) / u1.
// ---------------------------------------------------------------------------
__global__ __launch_bounds__(256, 2) void k_conv2(const __hip_bfloat16* __restrict__ xt,
                                                  const __hip_bfloat16* __restrict__ Bw2,
                                                  const float* __restrict__ pcb,
                                                  float* __restrict__ u0,
                                                  float* __restrict__ u1)
{
    const int pair = blockIdx.x >> 1;
    const int ks = blockIdx.x & 1;
    const int b0 = pair * 2;
    const int t = threadIdx.x;
    const int lane = t & 63, wc = t >> 6;
    const int r16 = lane & 15, slot = lane >> 4;

    __shared__ alignas(16) char xs[51200];

    int aimg[5], lc[5];
    #pragma unroll
    for (int mt = 0; mt < 5; ++mt) {
        int grow = mt * 16 + r16;
        int img = (grow >= 36 && grow < 72) ? 1 : 0;
        int hw = (grow < 72) ? (grow - 36 * img) : 0;
        int h = hw / 6, w = hw - h * 6;
        aimg[mt] = img * 25600;
        lc[mt] = 40 * h + w;
    }

    float4v acc[5][4];
    #pragma unroll
    for (int mt = 0; mt < 5; ++mt)
        #pragma unroll
        for (int nt = 0; nt < 4; ++nt)
            acc[mt][nt] = (float4v){0.f, 0.f, 0.f, 0.f};

    for (int i4 = 0; i4 < 4; ++i4) {
        const int icc = ks * 4 + i4;
        __syncthreads();
        stage_x(xt, xs, b0, icc, t);
        __syncthreads();

        const __hip_bfloat16* bp = Bw2 + ((size_t)icc * 4 + wc) * 2048 + lane * 8;

        #pragma unroll 3
        for (int kidx = 0; kidx < 81; ++kidx) {
            int ky = kidx / 9, kx = kidx - ky * 9;
            int scalK = 20 * ky + 10 * (kx & 1) + (kx >> 1);
            short8v a[5];
            #pragma unroll
            for (int mt = 0; mt < 5; ++mt) {
                int pos = lc[mt] + scalK;
                int off = aimg[mt] + pos * 64 + (((slot ^ (pos >> 1)) & 3) << 4);
                a[mt] = *(const short8v*)(xs + off);
            }
            const __hip_bfloat16* bq = bp + (size_t)kidx * 65536;
            short8v bv[4];
            #pragma unroll
            for (int nt = 0; nt < 4; ++nt)
                bv[nt] = *(const short8v*)(bq + nt * 512);
            #pragma unroll
            for (int mt = 0; mt < 5; ++mt)
                #pragma unroll
                for (int nt = 0; nt < 4; ++nt)
                    acc[mt][nt] = __builtin_amdgcn_mfma_f32_16x16x32_bf16(a[mt], bv[nt], acc[mt][nt], 0, 0, 0);
        }
    }

    float* uo = ks ? u1 : u0;
    #pragma unroll
    for (int mt = 0; mt < 5; ++mt) {
        int grow0 = mt * 16 + slot * 4;
        if (grow0 < 72) {
            int img = grow0 >= 36;
            int hwb = grow0 - 36 * img;
            const int b = b0 + img;
            #pragma unroll
            for (int nt = 0; nt < 4; ++nt) {
                int oc = wc * 64 + nt * 16 + r16;
                float pb = ks ? 0.f : pcb[oc];
                float4v v = acc[mt][nt];
                v.x += pb; v.y += pb; v.z += pb; v.w += pb;
                *(float4v*)(uo + (size_t)b * 9216 + oc * 36 + hwb) = v;
            }
        }
    }
}

// ---------------------------------------------------------------------------
// routing: grid 576 = 144 rc (8 W-rows) x 4 bc (128 images); 256 thr.
// u-tile staging fuses u0+u1 sum AND squash in-register.
// Thread = (oq, img) handles TWO images; W LDS-reads shared by both.
// ---------------------------------------------------------------------------
__global__ __launch_bounds__(256, 2) void k_route3(const float* __restrict__ u0,
                                                   const float* __restrict__ u1,
                                                   const float* __restrict__ W,
                                                   const float* __restrict__ vsum,
                                                   float* __restrict__ spart, int iter)
{
    const int bid = blockIdx.x;
    const int rc = bid % 144;
    const int bc = bid / 144;          // 0..3
    const int r0 = rc * 8;
    const int b0 = bc * 128;
    const int t = threadIdx.x;
    const int oq = t & 3;
    const int img = t >> 2;            // 0..63
    const int bA = b0 + img, bB = bA + 64;

    __shared__ alignas(16) float Wl[10240];     // 40KB: 8 rows x 320 f4, swizzled
    __shared__ alignas(16) float ul[128 * 68];  // 34.8KB: u tile, stride 68

    #pragma unroll
    for (int k = 0; k < 10; ++k) {
        int e = t + k * 256;
        int rr = e / 320, rest = e - rr * 320;
        float4v val = *(const float4v*)(W + (size_t)(r0 + rr) * 1280 + rest * 4);
        int es = e ^ ((e >> 3) & 3);
        *(float4v*)(Wl + es * 4) = val;
    }
    #pragma unroll
    for (int k = 0; k < 4; ++k) {
        int e = t + k * 256;
        int im = e >> 3, cap = e & 7;
        size_t gb = (size_t)(b0 + im) * 9216 + rc * 64 + cap * 8;
        const float4v* pA = (const float4v*)(u0 + gb);
        const float4v* pB = (const float4v*)(u1 + gb);
        float4v a = pA[0] + pB[0];
        float4v c = pA[1] + pB[1];
        float sq = a.x * a.x + a.y * a.y + a.z * a.z + a.w * a.w
                 + c.x * c.x + c.y * c.y + c.z * c.z + c.w * c.w;
        float scale = (sq / (1.f + sq)) / sqrtf(sq + EPSF);
        a *= scale; c *= scale;
        *(float4v*)(ul + im * 68 + cap * 8) = a;
        *(float4v*)(ul + im * 68 + cap * 8 + 4) = c;
    }
    __syncthreads();

    float4v accA[10], accB[10];
    #pragma unroll
    for (int j = 0; j < 10; ++j) {
        accA[j] = (float4v){0.f, 0.f, 0.f, 0.f};
        accB[j] = (float4v){0.f, 0.f, 0.f, 0.f};
    }

    const float* upA = ul + img * 68;
    const float* upB = ul + (img + 64) * 68;

    for (int r = 0; r < 8; ++r) {
        float4v uA0 = *(const float4v*)(upA + r * 8);
        float4v uA1 = *(const float4v*)(upA + r * 8 + 4);
        float4v uB0 = *(const float4v*)(upB + r * 8);
        float4v uB1 = *(const float4v*)(upB + r * 8 + 4);
        float4v uhA[10], uhB[10];
        #pragma unroll
        for (int j = 0; j < 10; ++j) {
            #pragma unroll
            for (int oo = 0; oo < 4; ++oo) {
                int un = r * 320 + j * 32 + oq * 8 + oo * 2;
                int i0 = un ^ oq;
                int i1 = i0 ^ 1;
                float4v wlo = *(const float4v*)(Wl + i0 * 4);
                float4v whi = *(const float4v*)(Wl + i1 * 4);
                uhA[j][oo] = wlo.x * uA0.x + wlo.y * uA0.y + wlo.z * uA0.z + wlo.w * uA0.w
                           + whi.x * uA1.x + whi.y * uA1.y + whi.z * uA1.z + whi.w * uA1.w;
                uhB[j][oo] = wlo.x * uB0.x + wlo.y * uB0.y + wlo.z * uB0.z + wlo.w * uB0.w
                           + whi.x * uB1.x + whi.y * uB1.y + whi.z * uB1.z + whi.w * uB1.w;
            }
        }
        if (iter > 0) {
            #pragma unroll 2
            for (int half = 0; half < 2; ++half) {
                const int b = half ? bB : bA;
                float4v* uh = half ? uhB : uhA;
                float4v* acc = half ? accB : accA;
                float q[10];
                #pragma unroll
                for (int j = 0; j < 10; ++j) {
                    float4v vj = *(const float4v*)(vsum + (size_t)b * 160 + j * 16 + oq * 4);
                    float qp = uh[j].x * vj.x + uh[j].y * vj.y
                             + uh[j].z * vj.z + uh[j].w * vj.w;
                    qp += __shfl_xor(qp, 1);
                    qp += __shfl_xor(qp, 2);
                    q[j] = qp;
                }
                float mx = q[0];
                #pragma unroll
                for (int j = 1; j < 10; ++j) mx = fmaxf(mx, q[j]);
                float ssum = 0.f;
                float c[10];
                #pragma unroll
                for (int j = 0; j < 10; ++j) { c[j] = __expf(q[j] - mx); ssum += c[j]; }
                float inv = 1.f / ssum;
                #pragma unroll
                for (int j = 0; j < 10; ++j) acc[j] += (c[j] * inv) * uh[j];
            }
        } else {
            #pragma unroll
            for (int j = 0; j < 10; ++j) {
                accA[j] += 0.1f * uhA[j];
                accB[j] += 0.1f * uhB[j];
            }
        }
    }

    float* dstA = spart + ((size_t)rc * 512 + bA) * 160 + oq * 4;
    float* dstB = spart + ((size_t)rc * 512 + bB) * 160 + oq * 4;
    #pragma unroll
    for (int j = 0; j < 10; ++j) {
        *(float4v*)(dstA + j * 16) = accA[j];
        *(float4v*)(dstB + j * 16) = accB[j];
    }
}

// ---------------------------------------------------------------------------
// finish: sum 144 partials -> squash -> v; vsum update; iter==2 writes outputs
// ---------------------------------------------------------------------------
__global__ void k_finish(const float* __restrict__ spart, float* __restrict__ vsum,
                         float* __restrict__ obj, float* __restrict__ yprob, int iter)
{
    const int b = blockIdx.x, t = threadIdx.x;
    if (t < 160) {
        const float* sp = spart + (size_t)b * 160 + t;
        float sv = 0.f;
        #pragma unroll 8
        for (int rc = 0; rc < 144; ++rc)
            sv += sp[(size_t)rc * 81920];
        float sq = sv * sv;
        sq += __shfl_xor(sq, 1); sq += __shfl_xor(sq, 2);
        sq += __shfl_xor(sq, 4); sq += __shfl_xor(sq, 8);
        float v = sv * (sq / (1.f + sq)) / sqrtf(sq + EPSF);
        float pv = (iter > 0) ? vsum[b * 160 + t] : 0.f;
        vsum[b * 160 + t] = pv + v;
        if (iter == 2) {
            obj[b * 160 + t] = v;
            float vv = v * v;
            vv += __shfl_xor(vv, 1); vv += __shfl_xor(vv, 2);
            vv += __shfl_xor(vv, 4); vv += __shfl_xor(vv, 8);
            if ((t & 15) == 0) yprob[b * 10 + (t >> 4)] = sqrtf(vv + EPSF);
        }
    }
}

// ---------------------------------------------------------------------------
// mlp1 with label-gather: h1[m][n] = relu(b1[n] + sum_{o<16} v[m][lab*16+o] *
// w1[n][lab*16+o]) — exploits one-hot mask (K=16 not 160). grid 64 (8 m each).
// ---------------------------------------------------------------------------
__global__ __launch_bounds__(256) void k_mlp1g(const float* __restrict__ obj,
                                               const int* __restrict__ label,
                                               const float* __restrict__ w1,
                                               const float* __restrict__ b1,
                                               float* __restrict__ h1)
{
    const int b0 = blockIdx.x * 8;
    const int t = threadIdx.x;
    __shared__ float vl[8][16];
    __shared__ int labs[8];
    if (t < 8) labs[t] = label[b0 + t];
    __syncthreads();
    if (t < 128) {
        int m = t >> 4, o = t & 15;
        vl[m][o] = obj[(size_t)(b0 + m) * 160 + labs[m] * 16 + o];
    }
    __syncthreads();
    #pragma unroll 2
    for (int nn = 0; nn < 2; ++nn) {
        const int n = t + nn * 256;
        const float bs = b1[n];
        #pragma unroll
        for (int m = 0; m < 8; ++m) {
            const float4v* wp = (const float4v*)(w1 + (size_t)n * 160 + labs[m] * 16);
            float4v w0 = wp[0], w1v = wp[1], w2 = wp[2], w3 = wp[3];
            float q = bs;
            q += vl[m][0]  * w0.x  + vl[m][1]  * w0.y  + vl[m][2]  * w0.z  + vl[m][3]  * w0.w;
            q += vl[m][4]  * w1v.x + vl[m][5]  * w1v.y + vl[m][6]  * w1v.z + vl[m][7]  * w1v.w;
            q += vl[m][8]  * w2.x  + vl[m][9]  * w2.y  + vl[m][10] * w2.z  + vl[m][11] * w2.w;
            q += vl[m][12] * w3.x  + vl[m][13] * w3.y  + vl[m][14] * w3.z  + vl[m][15] * w3.w;
            h1[(size_t)(b0 + m) * 512 + n] = fmaxf(q, 0.f);
        }
    }
}

// ---------------------------------------------------------------------------
// decoder GEMM (f32): C[m,n] = act(bias[n] + sum_k A[m,k]*Wt[n,k]); M=512.
// ---------------------------------------------------------------------------
__global__ void k_mlp(const float* __restrict__ A, const float* __restrict__ Wt,
                      const float* __restrict__ bias, float* __restrict__ C,
                      int N, int K, int act)
{
    const int m0 = blockIdx.x * 32;
    const int n0 = blockIdx.y * 32;
    const int t  = threadIdx.x;
    const int tn = t & 31, tg = t >> 5;
    __shared__ float As[32][33];
    __shared__ float Ws[32][33];
    float acc[4] = {0.f, 0.f, 0.f, 0.f};
    for (int k0 = 0; k0 < K; k0 += 32) {
        __syncthreads();
        for (int idx = t; idx < 1024; idx += 256) {
            int rr = idx >> 5, kk = idx & 31;
            As[rr][kk] = A[(size_t)(m0 + rr) * K + k0 + kk];
            int n = n0 + rr;
            Ws[rr][kk] = (n < N) ? Wt[(size_t)n * K + k0 + kk] : 0.f;
        }
        __syncthreads();
        #pragma unroll 8
        for (int kk = 0; kk < 32; ++kk) {
            float bv = Ws[tn][kk];
            #pragma unroll
            for (int i = 0; i < 4; ++i)
                acc[i] += As[tg * 4 + i][kk] * bv;
        }
    }
    int n = n0 + tn;
    if (n < N) {
        float bs = bias[n];
        #pragma unroll
        for (int i = 0; i < 4; ++i) {
            float vv = acc[i] + bs;
            vv = (act == 0) ? fmaxf(vv, 0.f) : 1.f / (1.f + expf(-vv));
            C[(size_t)(m0 + tg * 4 + i) * N + n] = vv;
        }
    }
}

// ---------------------------------------------------------------------------
extern "C" void kernel_launch(void* const* d_in, const int* in_sizes, int n_in,
                              void* d_out, int out_size, void* d_ws, size_t ws_size,
                              hipStream_t stream)
{
    const float* image  = (const float*)d_in[0];
    const int*   label  = (const int*)  d_in[1];
    const float* conv_w = (const float*)d_in[2];
    const float* conv_b = (const float*)d_in[3];
    const float* pc_w   = (const float*)d_in[4];
    const float* pc_b   = (const float*)d_in[5];
    const float* Wrt    = (const float*)d_in[6];
    const float* dw1 = (const float*)d_in[7];
    const float* db1 = (const float*)d_in[8];
    const float* dw2 = (const float*)d_in[9];
    const float* db2 = (const float*)d_in[10];
    const float* dw3 = (const float*)d_in[11];
    const float* db3 = (const float*)d_in[12];
    float* out = (float*)d_out;

    char* p = (char*)d_ws;
    __hip_bfloat16* xt  = (__hip_bfloat16*)p; p += 104857600;
    float* u      = (float*)p; p += 18874368;   // u0 (ks0 partial + bias)
    float* u1     = (float*)p; p += 18874368;   // ks1 partial
    __hip_bfloat16* Bw2 = (__hip_bfloat16*)p; p += 10616832;
    float* vsum   = (float*)p; p += 327680;
    float* h1     = (float*)p; p += 1048576;
    float* h2     = (float*)p; p += 2097152;

    // spart [144][512][160] f32 (47.2 MB) aliases xt (dead after k_conv2,
    // fully rewritten by k_prep each launch -> deterministic across replays).
    float* spart = (float*)xt;

    float* obj   = out;            // [512,10,16,1]
    float* recon = out + 81920;    // [512,1,28,28]
    float* yprob = out + 483328;   // [512,10]

    k_prep<<<768, 256, 0, stream>>>(pc_w, Bw2, image, conv_w, conv_b, xt);
    k_conv2<<<512, 256, 0, stream>>>(xt, Bw2, pc_b, u, u1);
    for (int it = 0; it < 3; ++it) {
        k_route3<<<576, 256, 0, stream>>>(u, u1, Wrt, vsum, spart, it);
        k_finish<<<512, 192, 0, stream>>>(spart, vsum, obj, yprob, it);
    }
    k_mlp1g<<<64, 256, 0, stream>>>(obj, label, dw1, db1, h1);
    k_mlp<<<dim3(16, 32), 256, 0, stream>>>(h1, dw2, db2, h2, 1024, 512, 0);
    k_mlp<<<dim3(16, 25), 256, 0, stream>>>(h2, dw3, db3, recon, 784, 1024, 1);
}

// Round 23
// 632.444 us; speedup vs baseline: 1.3791x; 1.0109x over previous
//
#include <hip/hip_runtime.h>
#include <hip/hip_bf16.h>

#define EPSF 1e-8f

typedef __attribute__((ext_vector_type(8))) short short8v;
typedef __attribute__((ext_vector_type(4))) float float4v;

static __device__ __forceinline__ unsigned short f2bf_bits(float x)
{
    return __builtin_bit_cast(unsigned short, __float2bfloat16(x));
}

// ---------------------------------------------------------------------------
// k_prep: fused bw2 (blocks 0-255) + conv1-MFMA (blocks 256-767).
// bw2: pc_w f32 -> Bw2 coalesced per-wave chunks.
// conv1: im2col MFMA GEMM per image: M=400 pos (25x16), N=256 ch, K=81->96.
// ---------------------------------------------------------------------------
__global__ __launch_bounds__(256) void k_prep(const float* __restrict__ pw,
                                              __hip_bfloat16* __restrict__ Bw2,
                                              const float* __restrict__ img,
                                              const float* __restrict__ cw,
                                              const float* __restrict__ cb,
                                              __hip_bfloat16* __restrict__ xt)
{
    __shared__ alignas(16) char shmem[54016];
    const int bid = blockIdx.x;
    const int t = threadIdx.x;

    if (bid < 256) {
        // ---- bw2 ----
        const int oc = bid;
        unsigned short* wl = (unsigned short*)shmem;   // [ic][k] bf16 bits
        for (int i = t; i < 20736; i += 256)
            wl[i] = f2bf_bits(pw[(size_t)oc * 20736 + i]);
        __syncthreads();
        const int r16 = oc & 15, nt = (oc >> 4) & 3, wcq = oc >> 6;
        for (int e = t; e < 2592; e += 256) {
            const int kidx = e >> 5, icc = (e >> 2) & 7, slot = e & 3;
            short8v v;
            #pragma unroll
            for (int i = 0; i < 8; ++i)
                v[i] = (short)wl[(icc * 32 + slot * 8 + i) * 81 + kidx];
            const int chunk = ((kidx * 8 + icc) * 4 + wcq) * 4 + nt;
            *(short8v*)(Bw2 + (size_t)chunk * 512 + (slot * 16 + r16) * 8) = v;
        }
        return;
    }

    // ---- conv1 via MFMA ----
    const int b = bid - 256;
    const int lane = t & 63, wid = t >> 6;
    const int r16 = lane & 15, slot = lane >> 4;

    unsigned short* simgbf = (unsigned short*)shmem;            // [1600] bf16
    int* offT             = (int*)(shmem + 3200);               // [96]
    unsigned short* Bw1c  = (unsigned short*)(shmem + 3584);    // [12*2056]
    float* cbl            = (float*)(shmem + 52928);            // [256]

    for (int i = t; i < 784; i += 256) simgbf[i] = f2bf_bits(img[b * 784 + i]);
    for (int i = 784 + t; i < 1600; i += 256) simgbf[i] = 0;
    if (t < 96) offT[t] = (t < 81) ? (t / 9) * 28 + (t % 9) : 1000;
    cbl[t] = cb[t];
    for (int e = t; e < 3072; e += 256) {
        const int chunk = e >> 8, c = e & 255;
        #pragma unroll
        for (int i = 0; i < 8; ++i) {
            const int k = chunk * 8 + i;
            Bw1c[chunk * 2056 + c * 8 + i] =
                (k < 81) ? f2bf_bits(cw[c * 81 + k]) : (unsigned short)0;
        }
    }
    __syncthreads();

    char* xb = (char*)xt + (size_t)b * 8 * 25600;

    for (int m = wid; m < 25; m += 4) {
        const int pos_r = m * 16 + r16;
        const int hh = (pos_r * 3277) >> 16;          // pos_r / 20
        const int ww = pos_r - hh * 20;
        const int abase = hh * 28 + ww;
        short8v a[3];
        #pragma unroll
        for (int ks = 0; ks < 3; ++ks) {
            #pragma unroll
            for (int i = 0; i < 8; ++i) {
                const int k = ks * 32 + slot * 8 + i;
                a[ks][i] = (short)simgbf[abase + offT[k]];
            }
        }
        #pragma unroll 4
        for (int nt = 0; nt < 16; ++nt) {
            float4v acc4 = (float4v){0.f, 0.f, 0.f, 0.f};
            #pragma unroll
            for (int ks = 0; ks < 3; ++ks) {
                short8v bv = *(const short8v*)(Bw1c + (ks * 4 + slot) * 2056
                                               + (nt * 16 + r16) * 8);
                acc4 = __builtin_amdgcn_mfma_f32_16x16x32_bf16(a[ks], bv, acc4, 0, 0, 0);
            }
            const int c = nt * 16 + r16;
            const int icc_ = c >> 5, sl = (c >> 3) & 3, i8 = c & 7;
            const float cbv = cbl[c];
            char* xc = xb + icc_ * 25600 + i8 * 2;
            #pragma unroll
            for (int i = 0; i < 4; ++i) {
                const int pos = m * 16 + slot * 4 + i;
                const int h2 = (pos * 3277) >> 16;
                const int w2 = pos - h2 * 20;
                const int pp = h2 * 20 + (w2 & 1) * 10 + (w2 >> 1);
                const float v = fmaxf(acc4[i] + cbv, 0.f);
                *(unsigned short*)(xc + pp * 64 + ((sl ^ ((pp >> 1) & 3)) << 4)) = f2bf_bits(v);
            }
        }
    }
}

// ---------------------------------------------------------------------------
// async stage of one icc-chunk (2 images, 51200 B) into LDS; 256 threads.
// ---------------------------------------------------------------------------
__device__ __forceinline__ void stage_x(const __hip_bfloat16* __restrict__ xt,
                                        char* dst, int b0, int icc, int t)
{
    const __hip_bfloat16* base0 = xt + ((size_t)(b0    ) * 8 + icc) * 12800;
    const __hip_bfloat16* base1 = xt + ((size_t)(b0 + 1) * 8 + icc) * 12800;
    #pragma unroll
    for (int k = 0; k < 12; ++k) {
        const int unit = t + k * 256;
        const __hip_bfloat16* gp = (unit < 1600) ? (base0 + unit * 8)
                                                 : (base1 + (unit - 1600) * 8);
        __builtin_amdgcn_global_load_lds(
            (const __attribute__((address_space(1))) unsigned int*)gp,
            (__attribute__((address_space(3))) unsigned int*)(dst + unit * 16),
            16, 0, 0);
    }
    if (t < 128) {
        const int unit = 3072 + t;
        const __hip_bfloat16* gp = base1 + (unit - 1600) * 8;
        __builtin_amdgcn_global_load_lds(
            (const __attribute__((address_space(1))) unsigned int*)gp,
            (__attribute__((address_space(3))) unsigned int*)(dst + unit * 16),
            16, 0, 0);
    }
}

// ---------------------------------------------------------------------------
// conv2 via MFMA, packed-M + K-split: grid 512 = 256 pairs x 2 ks (4 icc each).
// 256 thr = 4 waves (wc). Rows of BOTH images packed into 5 shared 16-row
// tiles -> 20 MFMA per 4KB B-load. Partials -> u0 (ks0,+bias) / u1.
// ---------------------------------------------------------------------------
__global__ __launch_bounds__(256, 2) void k_conv2(const __hip_bfloat16* __restrict__ xt,
                                                  const __hip_bfloat16* __restrict__ Bw2,
                                                  const float* __restrict__ pcb,
                                                  float* __restrict__ u0,
                                                  float* __restrict__ u1)
{
    const int pair = blockIdx.x >> 1;
    const int ks = blockIdx.x & 1;
    const int b0 = pair * 2;
    const int t = threadIdx.x;
    const int lane = t & 63, wc = t >> 6;
    const int r16 = lane & 15, slot = lane >> 4;

    __shared__ alignas(16) char xs[51200];

    int aimg[5], lc[5];
    #pragma unroll
    for (int mt = 0; mt < 5; ++mt) {
        int grow = mt * 16 + r16;
        int img = (grow >= 36 && grow < 72) ? 1 : 0;
        int hw = (grow < 72) ? (grow - 36 * img) : 0;
        int h = hw / 6, w = hw - h * 6;
        aimg[mt] = img * 25600;
        lc[mt] = 40 * h + w;
    }

    float4v acc[5][4];
    #pragma unroll
    for (int mt = 0; mt < 5; ++mt)
        #pragma unroll
        for (int nt = 0; nt < 4; ++nt)
            acc[mt][nt] = (float4v){0.f, 0.f, 0.f, 0.f};

    for (int i4 = 0; i4 < 4; ++i4) {
        const int icc = ks * 4 + i4;
        __syncthreads();
        stage_x(xt, xs, b0, icc, t);
        __syncthreads();

        const __hip_bfloat16* bp = Bw2 + ((size_t)icc * 4 + wc) * 2048 + lane * 8;

        #pragma unroll 3
        for (int kidx = 0; kidx < 81; ++kidx) {
            int ky = kidx / 9, kx = kidx - ky * 9;
            int scalK = 20 * ky + 10 * (kx & 1) + (kx >> 1);
            short8v a[5];
            #pragma unroll
            for (int mt = 0; mt < 5; ++mt) {
                int pos = lc[mt] + scalK;
                int off = aimg[mt] + pos * 64 + (((slot ^ (pos >> 1)) & 3) << 4);
                a[mt] = *(const short8v*)(xs + off);
            }
            const __hip_bfloat16* bq = bp + (size_t)kidx * 65536;
            short8v bv[4];
            #pragma unroll
            for (int nt = 0; nt < 4; ++nt)
                bv[nt] = *(const short8v*)(bq + nt * 512);
            #pragma unroll
            for (int mt = 0; mt < 5; ++mt)
                #pragma unroll
                for (int nt = 0; nt < 4; ++nt)
                    acc[mt][nt] = __builtin_amdgcn_mfma_f32_16x16x32_bf16(a[mt], bv[nt], acc[mt][nt], 0, 0, 0);
        }
    }

    float* uo = ks ? u1 : u0;
    #pragma unroll
    for (int mt = 0; mt < 5; ++mt) {
        int grow0 = mt * 16 + slot * 4;
        if (grow0 < 72) {
            int img = grow0 >= 36;
            int hwb = grow0 - 36 * img;
            const int b = b0 + img;
            #pragma unroll
            for (int nt = 0; nt < 4; ++nt) {
                int oc = wc * 64 + nt * 16 + r16;
                float pb = ks ? 0.f : pcb[oc];
                float4v v = acc[mt][nt];
                v.x += pb; v.y += pb; v.z += pb; v.w += pb;
                *(float4v*)(uo + (size_t)b * 9216 + oc * 36 + hwb) = v;
            }
        }
    }
}

// ---------------------------------------------------------------------------
// routing: grid 576 = 144 rc (8 W-rows) x 4 bc (128 images); 256 thr.
// u-tile staging fuses u0+u1 sum AND squash in-register.
// Thread = (oq, img) handles TWO images; W LDS-reads shared by both.
// ---------------------------------------------------------------------------
__global__ __launch_bounds__(256, 2) void k_route3(const float* __restrict__ u0,
                                                   const float* __restrict__ u1,
                                                   const float* __restrict__ W,
                                                   const float* __restrict__ vsum,
                                                   float* __restrict__ spart, int iter)
{
    const int bid = blockIdx.x;
    const int rc = bid % 144;
    const int bc = bid / 144;          // 0..3
    const int r0 = rc * 8;
    const int b0 = bc * 128;
    const int t = threadIdx.x;
    const int oq = t & 3;
    const int img = t >> 2;            // 0..63
    const int bA = b0 + img, bB = bA + 64;

    __shared__ alignas(16) float Wl[10240];     // 40KB: 8 rows x 320 f4, swizzled
    __shared__ alignas(16) float ul[128 * 68];  // 34.8KB: u tile, stride 68

    #pragma unroll
    for (int k = 0; k < 10; ++k) {
        int e = t + k * 256;
        int rr = e / 320, rest = e - rr * 320;
        float4v val = *(const float4v*)(W + (size_t)(r0 + rr) * 1280 + rest * 4);
        int es = e ^ ((e >> 3) & 3);
        *(float4v*)(Wl + es * 4) = val;
    }
    #pragma unroll
    for (int k = 0; k < 4; ++k) {
        int e = t + k * 256;
        int im = e >> 3, cap = e & 7;
        size_t gb = (size_t)(b0 + im) * 9216 + rc * 64 + cap * 8;
        const float4v* pA = (const float4v*)(u0 + gb);
        const float4v* pB = (const float4v*)(u1 + gb);
        float4v a = pA[0] + pB[0];
        float4v c = pA[1] + pB[1];
        float sq = a.x * a.x + a.y * a.y + a.z * a.z + a.w * a.w
                 + c.x * c.x + c.y * c.y + c.z * c.z + c.w * c.w;
        float scale = (sq / (1.f + sq)) / sqrtf(sq + EPSF);
        a *= scale; c *= scale;
        *(float4v*)(ul + im * 68 + cap * 8) = a;
        *(float4v*)(ul + im * 68 + cap * 8 + 4) = c;
    }
    __syncthreads();

    float4v accA[10], accB[10];
    #pragma unroll
    for (int j = 0; j < 10; ++j) {
        accA[j] = (float4v){0.f, 0.f, 0.f, 0.f};
        accB[j] = (float4v){0.f, 0.f, 0.f, 0.f};
    }

    const float* upA = ul + img * 68;
    const float* upB = ul + (img + 64) * 68;

    for (int r = 0; r < 8; ++r) {
        float4v uA0 = *(const float4v*)(upA + r * 8);
        float4v uA1 = *(const float4v*)(upA + r * 8 + 4);
        float4v uB0 = *(const float4v*)(upB + r * 8);
        float4v uB1 = *(const float4v*)(upB + r * 8 + 4);
        float4v uhA[10], uhB[10];
        #pragma unroll
        for (int j = 0; j < 10; ++j) {
            #pragma unroll
            for (int oo = 0; oo < 4; ++oo) {
                int un = r * 320 + j * 32 + oq * 8 + oo * 2;
                int i0 = un ^ oq;
                int i1 = i0 ^ 1;
                float4v wlo = *(const float4v*)(Wl + i0 * 4);
                float4v whi = *(const float4v*)(Wl + i1 * 4);
                uhA[j][oo] = wlo.x * uA0.x + wlo.y * uA0.y + wlo.z * uA0.z + wlo.w * uA0.w
                           + whi.x * uA1.x + whi.y * uA1.y + whi.z * uA1.z + whi.w * uA1.w;
                uhB[j][oo] = wlo.x * uB0.x + wlo.y * uB0.y + wlo.z * uB0.z + wlo.w * uB0.w
                           + whi.x * uB1.x + whi.y * uB1.y + whi.z * uB1.z + whi.w * uB1.w;
            }
        }
        if (iter > 0) {
            #pragma unroll 2
            for (int half = 0; half < 2; ++half) {
                const int b = half ? bB : bA;
                float4v* uh = half ? uhB : uhA;
                float4v* acc = half ? accB : accA;
                float q[10];
                #pragma unroll
                for (int j = 0; j < 10; ++j) {
                    float4v vj = *(const float4v*)(vsum + (size_t)b * 160 + j * 16 + oq * 4);
                    float qp = uh[j].x * vj.x + uh[j].y * vj.y
                             + uh[j].z * vj.z + uh[j].w * vj.w;
                    qp += __shfl_xor(qp, 1);
                    qp += __shfl_xor(qp, 2);
                    q[j] = qp;
                }
                float mx = q[0];
                #pragma unroll
                for (int j = 1; j < 10; ++j) mx = fmaxf(mx, q[j]);
                float ssum = 0.f;
                float c[10];
                #pragma unroll
                for (int j = 0; j < 10; ++j) { c[j] = __expf(q[j] - mx); ssum += c[j]; }
                float inv = 1.f / ssum;
                #pragma unroll
                for (int j = 0; j < 10; ++j) acc[j] += (c[j] * inv) * uh[j];
            }
        } else {
            #pragma unroll
            for (int j = 0; j < 10; ++j) {
                accA[j] += 0.1f * uhA[j];
                accB[j] += 0.1f * uhB[j];
            }
        }
    }

    float* dstA = spart + ((size_t)rc * 512 + bA) * 160 + oq * 4;
    float* dstB = spart + ((size_t)rc * 512 + bB) * 160 + oq * 4;
    #pragma unroll
    for (int j = 0; j < 10; ++j) {
        *(float4v*)(dstA + j * 16) = accA[j];
        *(float4v*)(dstB + j * 16) = accB[j];
    }
}

// ---------------------------------------------------------------------------
// finish: sum 144 partials -> squash -> v; vsum update; iter==2 writes outputs
// ---------------------------------------------------------------------------
__global__ void k_finish(const float* __restrict__ spart, float* __restrict__ vsum,
                         float* __restrict__ obj, float* __restrict__ yprob, int iter)
{
    const int b = blockIdx.x, t = threadIdx.x;
    if (t < 160) {
        const float* sp = spart + (size_t)b * 160 + t;
        float sv = 0.f;
        #pragma unroll 8
        for (int rc = 0; rc < 144; ++rc)
            sv += sp[(size_t)rc * 81920];
        float sq = sv * sv;
        sq += __shfl_xor(sq, 1); sq += __shfl_xor(sq, 2);
        sq += __shfl_xor(sq, 4); sq += __shfl_xor(sq, 8);
        float v = sv * (sq / (1.f + sq)) / sqrtf(sq + EPSF);
        float pv = (iter > 0) ? vsum[b * 160 + t] : 0.f;
        vsum[b * 160 + t] = pv + v;
        if (iter == 2) {
            obj[b * 160 + t] = v;
            float vv = v * v;
            vv += __shfl_xor(vv, 1); vv += __shfl_xor(vv, 2);
            vv += __shfl_xor(vv, 4); vv += __shfl_xor(vv, 8);
            if ((t & 15) == 0) yprob[b * 10 + (t >> 4)] = sqrtf(vv + EPSF);
        }
    }
}

// ---------------------------------------------------------------------------
// mlp1 with label-gather: h1[m][n] = relu(b1[n] + sum_{o<16} v[m][lab*16+o] *
// w1[n][lab*16+o]) — exploits one-hot mask (K=16 not 160). grid 64 (8 m each).
// ---------------------------------------------------------------------------
__global__ __launch_bounds__(256) void k_mlp1g(const float* __restrict__ obj,
                                               const int* __restrict__ label,
                                               const float* __restrict__ w1,
                                               const float* __restrict__ b1,
                                               float* __restrict__ h1)
{
    const int b0 = blockIdx.x * 8;
    const int t = threadIdx.x;
    __shared__ float vl[8][16];
    __shared__ int labs[8];
    if (t < 8) labs[t] = label[b0 + t];
    __syncthreads();
    if (t < 128) {
        int m = t >> 4, o = t & 15;
        vl[m][o] = obj[(size_t)(b0 + m) * 160 + labs[m] * 16 + o];
    }
    __syncthreads();
    #pragma unroll 2
    for (int nn = 0; nn < 2; ++nn) {
        const int n = t + nn * 256;
        const float bs = b1[n];
        #pragma unroll
        for (int m = 0; m < 8; ++m) {
            const float4v* wp = (const float4v*)(w1 + (size_t)n * 160 + labs[m] * 16);
            float4v w0 = wp[0], w1v = wp[1], w2 = wp[2], w3 = wp[3];
            float q = bs;
            q += vl[m][0]  * w0.x  + vl[m][1]  * w0.y  + vl[m][2]  * w0.z  + vl[m][3]  * w0.w;
            q += vl[m][4]  * w1v.x + vl[m][5]  * w1v.y + vl[m][6]  * w1v.z + vl[m][7]  * w1v.w;
            q += vl[m][8]  * w2.x  + vl[m][9]  * w2.y  + vl[m][10] * w2.z  + vl[m][11] * w2.w;
            q += vl[m][12] * w3.x  + vl[m][13] * w3.y  + vl[m][14] * w3.z  + vl[m][15] * w3.w;
            h1[(size_t)(b0 + m) * 512 + n] = fmaxf(q, 0.f);
        }
    }
}

// ---------------------------------------------------------------------------
// decoder GEMM (f32): C[m,n] = act(bias[n] + sum_k A[m,k]*Wt[n,k]); M=512.
// ---------------------------------------------------------------------------
__global__ void k_mlp(const float* __restrict__ A, const float* __restrict__ Wt,
                      const float* __restrict__ bias, float* __restrict__ C,
                      int N, int K, int act)
{
    const int m0 = blockIdx.x * 32;
    const int n0 = blockIdx.y * 32;
    const int t  = threadIdx.x;
    const int tn = t & 31, tg = t >> 5;
    __shared__ float As[32][33];
    __shared__ float Ws[32][33];
    float acc[4] = {0.f, 0.f, 0.f, 0.f};
    for (int k0 = 0; k0 < K; k0 += 32) {
        __syncthreads();
        for (int idx = t; idx < 1024; idx += 256) {
            int rr = idx >> 5, kk = idx & 31;
            As[rr][kk] = A[(size_t)(m0 + rr) * K + k0 + kk];
            int n = n0 + rr;
            Ws[rr][kk] = (n < N) ? Wt[(size_t)n * K + k0 + kk] : 0.f;
        }
        __syncthreads();
        #pragma unroll 8
        for (int kk = 0; kk < 32; ++kk) {
            float bv = Ws[tn][kk];
            #pragma unroll
            for (int i = 0; i < 4; ++i)
                acc[i] += As[tg * 4 + i][kk] * bv;
        }
    }
    int n = n0 + tn;
    if (n < N) {
        float bs = bias[n];
        #pragma unroll
        for (int i = 0; i < 4; ++i) {
            float vv = acc[i] + bs;
            vv = (act == 0) ? fmaxf(vv, 0.f) : 1.f / (1.f + expf(-vv));
            C[(size_t)(m0 + tg * 4 + i) * N + n] = vv;
        }
    }
}

// ---------------------------------------------------------------------------
extern "C" void kernel_launch(void* const* d_in, const int* in_sizes, int n_in,
                              void* d_out, int out_size, void* d_ws, size_t ws_size,
                              hipStream_t stream)
{
    const float* image  = (const float*)d_in[0];
    const int*   label  = (const int*)  d_in[1];
    const float* conv_w = (const float*)d_in[2];
    const float* conv_b = (const float*)d_in[3];
    const float* pc_w   = (const float*)d_in[4];
    const float* pc_b   = (const float*)d_in[5];
    const float* Wrt    = (const float*)d_in[6];
    const float* dw1 = (const float*)d_in[7];
    const float* db1 = (const float*)d_in[8];
    const float* dw2 = (const float*)d_in[9];
    const float* db2 = (const float*)d_in[10];
    const float* dw3 = (const float*)d_in[11];
    const float* db3 = (const float*)d_in[12];
    float* out = (float*)d_out;

    char* p = (char*)d_ws;
    __hip_bfloat16* xt  = (__hip_bfloat16*)p; p += 104857600;
    float* u      = (float*)p; p += 18874368;   // u0 (ks0 partial + bias)
    float* u1     = (float*)p; p += 18874368;   // ks1 partial
    __hip_bfloat16* Bw2 = (__hip_bfloat16*)p; p += 10616832;
    float* vsum   = (float*)p; p += 327680;
    float* h1     = (float*)p; p += 1048576;
    float* h2     = (float*)p; p += 2097152;

    // spart [144][512][160] f32 (47.2 MB) aliases xt (dead after k_conv2,
    // fully rewritten by k_prep each launch -> deterministic across replays).
    float* spart = (float*)xt;

    float* obj   = out;            // [512,10,16,1]
    float* recon = out + 81920;    // [512,1,28,28]
    float* yprob = out + 483328;   // [512,10]

    k_prep<<<768, 256, 0, stream>>>(pc_w, Bw2, image, conv_w, conv_b, xt);
    k_conv2<<<512, 256, 0, stream>>>(xt, Bw2, pc_b, u, u1);
    for (int it = 0; it < 3; ++it) {
        k_route3<<<576, 256, 0, stream>>>(u, u1, Wrt, vsum, spart, it);
        k_finish<<<512, 192, 0, stream>>>(spart, vsum, obj, yprob, it);
    }
    k_mlp1g<<<64, 256, 0, stream>>>(obj, label, dw1, db1, h1);
    k_mlp<<<dim3(16, 32), 256, 0, stream>>>(h1, dw2, db2, h2, 1024, 512, 0);
    k_mlp<<<dim3(16, 25), 256, 0, stream>>>(h2, dw3, db3, recon, 784, 1024, 1);
}